// Round 4
// baseline (249.346 us; speedup 1.0000x reference)
//
#include <hip/hip_runtime.h>
#include <hip/hip_bf16.h>
#include <cfloat>
#include <math.h>

#define NFULL 4096
#define NPOOL 1024
#define NTOK  5120
#define VDIM  4096

typedef __attribute__((ext_vector_type(8))) short short8;   // 8 bf16 (4 VGPR)
typedef __attribute__((ext_vector_type(4))) float f4;       // MFMA acc
typedef unsigned long long u64;

#define MFMA16(a,b,c) __builtin_amdgcn_mfma_f32_16x16x32_bf16((a),(b),(c),0,0,0)

static __device__ __forceinline__ void gl_lds16(const void* g, void* l) {
    __builtin_amdgcn_global_load_lds(
        (const __attribute__((address_space(1))) unsigned int*)g,
        (__attribute__((address_space(3))) unsigned int*)l, 16, 0, 0);
}

// ==== bf16 MFMA 128x128 core, BK=64, XOR-swizzled LDS (r4-verified) ========
// Requires As, Bs to span 128*64 bf16 (16 KB) EACH.  Single-buffered,
// 2 barriers per K-step.  Used by mid2_k (keeps 32 KB LDS so the norm
// blocks in the same launch retain occupancy).
#define BGEMM3_CORE(AM, Bt)                                                    \
    int lane = tid & 63, w = tid >> 6, wy = w >> 1, wx = w & 1;                \
    int lm = lane & 15, quad = lane >> 4;                                      \
    int lr8 = lane >> 3;                                                       \
    int kcs = (lane & 7) ^ lr8;                                                \
    int rS = w * 32 + lr8;                                                     \
    const __hip_bfloat16* Ag = (AM) + (mB + rS) * 512 + kcs * 8;               \
    const __hip_bfloat16* Bg = (Bt) + (nB + rS) * 512 + kcs * 8;               \
    __hip_bfloat16* Al = As + (w * 32) * 64 + lane * 8;                        \
    __hip_bfloat16* Bl = Bs + (w * 32) * 64 + lane * 8;                        \
    f4 acc[4][4];                                                              \
    _Pragma("unroll") for (int i = 0; i < 4; ++i)                              \
        _Pragma("unroll") for (int j = 0; j < 4; ++j)                          \
            acc[i][j] = f4{0.f, 0.f, 0.f, 0.f};                                \
    int aswz = lm & 7;                                                         \
    for (int kt = 0; kt < 8; ++kt) {                                           \
        __syncthreads();                                                       \
        _Pragma("unroll") for (int i = 0; i < 4; ++i) {                        \
            gl_lds16(Ag + kt * 64 + i * 8 * 512, Al + i * 8 * 64);             \
            gl_lds16(Bg + kt * 64 + i * 8 * 512, Bl + i * 8 * 64);             \
        }                                                                      \
        __syncthreads();                                                       \
        _Pragma("unroll") for (int s = 0; s < 2; ++s) {                        \
            short8 aF[4], bF[4];                                               \
            int slot = ((s * 4 + quad) ^ aswz) << 3;                           \
            _Pragma("unroll") for (int mt = 0; mt < 4; ++mt)                   \
                aF[mt] = *(const short8*)(As + (wy * 64 + mt * 16 + lm) * 64 + slot); \
            _Pragma("unroll") for (int nt = 0; nt < 4; ++nt)                   \
                bF[nt] = *(const short8*)(Bs + (wx * 64 + nt * 16 + lm) * 64 + slot); \
            _Pragma("unroll") for (int mt = 0; mt < 4; ++mt)                   \
                _Pragma("unroll") for (int nt = 0; nt < 4; ++nt)               \
                    acc[mt][nt] = MFMA16(aF[mt], bF[nt], acc[mt][nt]);         \
        }                                                                      \
    }

// ======================= prep: transposes + casts + zero-init ==============
__global__ void prep_k(const float* __restrict__ z, const float* __restrict__ cbk,
                       const float* __restrict__ Wq, const float* __restrict__ Wv,
                       float* __restrict__ X, __hip_bfloat16* __restrict__ Xh,
                       __hip_bfloat16* __restrict__ cbh,
                       __hip_bfloat16* __restrict__ WqT, __hip_bfloat16* __restrict__ WvT,
                       u64* __restrict__ packed, unsigned int* __restrict__ Kmax2i) {
    __shared__ float smem[33 * 32];
    int bx = blockIdx.x;
    if (bx < 2048) {
        float (*tile)[33] = (float(*)[33])smem;
        int t0 = (bx & 31) * 32, c0 = ((bx >> 5) & 15) * 32, b = bx >> 9;
        int tx = threadIdx.x & 31, ty = threadIdx.x >> 5;
        #pragma unroll
        for (int i = 0; i < 4; ++i) {
            int c = ty + i * 8;
            tile[c][tx] = z[((b << 9) + c0 + c) * 1024 + t0 + tx];
        }
        __syncthreads();
        #pragma unroll
        for (int i = 0; i < 4; ++i) {
            int tl = ty + i * 8;
            int tok = (b << 10) + t0 + tl;
            Xh[tok * 512 + c0 + tx] = __float2bfloat16(tile[tx][tl]);
        }
        float m = 0.25f * (tile[tx][ty * 4] + tile[tx][ty * 4 + 1] +
                           tile[tx][ty * 4 + 2] + tile[tx][ty * 4 + 3]);
        int tq = (t0 >> 2) + ty;
        X[(NFULL + (b << 8) + tq) * 512 + c0 + tx] = m;
    } else if (bx < 4096) {
        int i0 = (bx - 2048) * 1024 + threadIdx.x * 4;
        float4 v = *(const float4*)(cbk + i0);
        __hip_bfloat16* d = cbh + i0;
        d[0] = __float2bfloat16(v.x); d[1] = __float2bfloat16(v.y);
        d[2] = __float2bfloat16(v.z); d[3] = __float2bfloat16(v.w);
    } else if (bx < 4608) {
        int lin = bx - 4096;
        const float* W = (lin >> 8) ? Wv : Wq;
        __hip_bfloat16* WT = (lin >> 8) ? WvT : WqT;
        float (*t)[33] = (float(*)[33])smem;
        int bk = ((lin >> 4) & 15) * 32, bn = (lin & 15) * 32;
        int lx = threadIdx.x & 31, ly = threadIdx.x >> 5;
        #pragma unroll
        for (int i = 0; i < 4; ++i) {
            int r = ly * 4 + i;
            t[r][lx] = W[(bk + r) * 512 + bn + lx];
        }
        __syncthreads();
        #pragma unroll
        for (int i = 0; i < 4; ++i) {
            int r = ly * 4 + i;
            WT[(bn + r) * 512 + bk + lx] = __float2bfloat16(t[lx][r]);
        }
    } else {
        int i = (bx - 4608) * 256 + threadIdx.x;     // 0..4095
        packed[i] = 0ull;
        if (bx == 4608 && threadIdx.x == 0) Kmax2i[0] = 0u;
    }
}

// ======================= mid1: fp32 proj | pool-c (both depend on prep) ====
__global__ __launch_bounds__(256) void mid1_k(
    const __hip_bfloat16* __restrict__ Xh,
    const float* __restrict__ cbk, const float* __restrict__ Xp,
    const float* __restrict__ Wk, const float* __restrict__ Wq,
    const float* __restrict__ Wp, const float* __restrict__ bp,
    float* __restrict__ P0, float* __restrict__ P1, float* __restrict__ Cp) {
    __shared__ __align__(16) char smraw[16640];
    int bx = blockIdx.x, tid = threadIdx.x;
    if (bx < 640) {
        // ---------------- fp32 split-K projection ---------------------------
        float (*As2)[68]  = (float(*)[68])smraw;
        float (*Bs2)[132] = (float(*)[132])(smraw + 16 * 68 * 4);
        int kz = bx >= 320;
        int rem = bx - kz * 320;
        int mB = (rem % 80) * 64, nB = (rem / 80) * 128, kOff = kz * 256;
        const float *A, *B;
        if (mB < NFULL) { A = cbk + mB * 512; B = Wk; }
        else            { A = Xp + (mB - NFULL) * 512; B = Wq; }
        int ty = tid >> 4, tx = tid & 15;
        int arow = tid >> 2, achk = tid & 3;
        int brow = tid >> 4, bcol = (tid & 15) * 4;
        const float* Ap = A + arow * 512 + kOff + achk * 4;
        const float* Bp = B + (kOff + brow) * 512 + nB + bcol;
        float acc[4][8] = {};
        for (int kt = 0; kt < 16; ++kt) {
            float4 a  = *(const float4*)(Ap + kt * 16);
            float4 b0 = *(const float4*)(Bp + kt * 16 * 512);
            float4 b1 = *(const float4*)(Bp + kt * 16 * 512 + 64);
            __syncthreads();
            As2[achk * 4 + 0][arow] = a.x; As2[achk * 4 + 1][arow] = a.y;
            As2[achk * 4 + 2][arow] = a.z; As2[achk * 4 + 3][arow] = a.w;
            *(float4*)&Bs2[brow][bcol]      = b0;
            *(float4*)&Bs2[brow][bcol + 64] = b1;
            __syncthreads();
            #pragma unroll
            for (int kk = 0; kk < 16; ++kk) {
                float4 av  = *(const float4*)&As2[kk][ty * 4];
                float4 bv0 = *(const float4*)&Bs2[kk][tx * 4];
                float4 bv1 = *(const float4*)&Bs2[kk][64 + tx * 4];
                float a4[4] = {av.x, av.y, av.z, av.w};
                float b8[8] = {bv0.x, bv0.y, bv0.z, bv0.w, bv1.x, bv1.y, bv1.z, bv1.w};
                #pragma unroll
                for (int i = 0; i < 4; ++i)
                    #pragma unroll
                    for (int j = 0; j < 8; ++j)
                        acc[i][j] = fmaf(a4[i], b8[j], acc[i][j]);
            }
        }
        float* P = kz ? P1 : P0;
        #pragma unroll
        for (int i = 0; i < 4; ++i) {
            int row = mB + ty * 4 + i;
            float4 r0, r1;
            r0.x = acc[i][0]; r0.y = acc[i][1]; r0.z = acc[i][2]; r0.w = acc[i][3];
            r1.x = acc[i][4]; r1.y = acc[i][5]; r1.z = acc[i][6]; r1.w = acc[i][7];
            *(float4*)&P[row * 512 + nB + tx * 4]      = r0;
            *(float4*)&P[row * 512 + nB + 64 + tx * 4] = r1;
        }
    } else {
        // ---------------- head-pool weights Cp ------------------------------
        float* Wl = (float*)smraw;             // 4160 floats: lane stride 65
        for (int i = tid; i < 4096; i += 256) Wl[i + (i >> 6)] = Wp[i];
        __syncthreads();
        int w = tid >> 6, lane = tid & 63;
        int tok = (bx - 640) * 4 + w;          // 0..5119
        float x[8];
        if (tok < NFULL) {
            short8 xv = *(const short8*)(Xh + tok * 512 + lane * 8);
            #pragma unroll
            for (int j = 0; j < 8; ++j)
                x[j] = __uint_as_float(((unsigned)(unsigned short)xv[j]) << 16);
        } else {
            const float* xp = Xp + (tok - NFULL) * 512 + lane * 8;
            float4 a = *(const float4*)xp, b = *(const float4*)(xp + 4);
            x[0] = a.x; x[1] = a.y; x[2] = a.z; x[3] = a.w;
            x[4] = b.x; x[5] = b.y; x[6] = b.z; x[7] = b.w;
        }
        float s[8] = {};
        int base = lane * 65;
        #pragma unroll
        for (int j = 0; j < 8; ++j)
            #pragma unroll
            for (int h = 0; h < 8; ++h)
                s[h] = fmaf(x[j], Wl[base + j * 8 + h], s[h]);
        #pragma unroll
        for (int h = 0; h < 8; ++h)
            #pragma unroll
            for (int o = 32; o > 0; o >>= 1) s[h] += __shfl_xor(s[h], o);
        if (lane == 0) {
            #pragma unroll
            for (int h = 0; h < 8; ++h) Cp[tok * 8 + h] = s[h] + bp[h];
        }
    }
}

// ======================= mid2: bf16 bgemms | split-K norm-finish ===========
// [0,256): MFMA GEMMs (Qproj+norm reads Cp - ordered after mid1; Vproj).
// [256,1536): norm-finish, WAVE-PER-ROW, 4 rows/block.
// NOTE: smraw MUST be 32768 B — BGEMM3_CORE uses As (16 KB) + Bs (16 KB).
__global__ __launch_bounds__(256) void mid2_k(
    const __hip_bfloat16* __restrict__ Xh, const __hip_bfloat16* __restrict__ WqT,
    const __hip_bfloat16* __restrict__ cbh, const __hip_bfloat16* __restrict__ WvT,
    const float* __restrict__ P0, const float* __restrict__ P1,
    const float* __restrict__ bk, const float* __restrict__ bq,
    const float* __restrict__ gk, const float* __restrict__ gq,
    const float* __restrict__ Cp, const float* __restrict__ bvv,
    __hip_bfloat16* __restrict__ Qh, float* __restrict__ Vb,
    float* __restrict__ Kn, __hip_bfloat16* __restrict__ Kh,
    float* __restrict__ Qpool, unsigned int* __restrict__ Kmax2i) {
    __shared__ __align__(16) char smraw[32768];
    int bx = blockIdx.x, tid = threadIdx.x;
    if (bx < 256) {
        int part = bx >> 7, rem = bx & 127;
        int mB = (rem & 31) * 128, nB = (rem >> 5) * 128;
        const __hip_bfloat16* AM = part ? cbh : Xh;
        const __hip_bfloat16* Bt = part ? WvT : WqT;
        __hip_bfloat16* As = (__hip_bfloat16*)smraw;
        __hip_bfloat16* Bs = As + 128 * 64;
        BGEMM3_CORE(AM, Bt)
        if (part == 0) {
            int h = (rem >> 5) * 2 + wx;
            float bb[4], gg[4];
            #pragma unroll
            for (int nt = 0; nt < 4; ++nt) {
                bb[nt] = bq[h * 64 + nt * 16 + lm];
                gg[nt] = gq[nt * 16 + lm];
            }
            #pragma unroll
            for (int mt = 0; mt < 4; ++mt)
                #pragma unroll
                for (int reg = 0; reg < 4; ++reg) {
                    int tok = mB + wy * 64 + mt * 16 + quad * 4 + reg;
                    float vv[4], ss = 0.f;
                    #pragma unroll
                    for (int nt = 0; nt < 4; ++nt) {
                        vv[nt] = acc[mt][nt][reg] + bb[nt];
                        ss = fmaf(vv[nt], vv[nt], ss);
                    }
                    #pragma unroll
                    for (int off = 1; off < 16; off <<= 1) ss += __shfl_xor(ss, off);
                    float sc = rsqrtf(ss * (1.0f / 64.0f) + 1e-5f) *
                               Cp[tok * 8 + h] * 0.04419417382415922f;  // 1/(8*sqrt8)
                    #pragma unroll
                    for (int nt = 0; nt < 4; ++nt)
                        Qh[tok * 512 + h * 64 + nt * 16 + lm] =
                            __float2bfloat16(vv[nt] * sc * gg[nt]);
                }
        } else {
            float bb[4];
            #pragma unroll
            for (int nt = 0; nt < 4; ++nt) bb[nt] = bvv[nB + wx * 64 + nt * 16 + lm];
            #pragma unroll
            for (int mt = 0; mt < 4; ++mt)
                #pragma unroll
                for (int reg = 0; reg < 4; ++reg) {
                    int m = mB + wy * 64 + mt * 16 + quad * 4 + reg;
                    #pragma unroll
                    for (int nt = 0; nt < 4; ++nt)
                        Vb[m * 512 + nB + wx * 64 + nt * 16 + lm] =
                            acc[mt][nt][reg] + bb[nt];
                }
        }
    } else {
        // ---------------- split-K reduce + rmsnorm (wave-per-row) -----------
        int w = tid >> 6, lane = tid & 63;
        int row = (bx - 256) * 4 + w;      // 0..5119
        bool isQ = row >= NFULL;
        const float* bias = isQ ? bq : bk;
        const float* g = isQ ? gq : gk;
        int c0 = lane * 8;                 // 8 contiguous cols per lane
        const float* p0 = P0 + row * 512 + c0;
        const float* p1 = P1 + row * 512 + c0;
        float4 a0 = *(const float4*)p0,  a1 = *(const float4*)(p0 + 4);
        float4 d0 = *(const float4*)p1,  d1 = *(const float4*)(p1 + 4);
        float4 e0 = *(const float4*)(bias + c0), e1 = *(const float4*)(bias + c0 + 4);
        int gi = (lane & 7) * 8;
        float4 g0 = *(const float4*)(g + gi), g1 = *(const float4*)(g + gi + 4);
        float v[8];
        v[0] = a0.x + d0.x + e0.x; v[1] = a0.y + d0.y + e0.y;
        v[2] = a0.z + d0.z + e0.z; v[3] = a0.w + d0.w + e0.w;
        v[4] = a1.x + d1.x + e1.x; v[5] = a1.y + d1.y + e1.y;
        v[6] = a1.z + d1.z + e1.z; v[7] = a1.w + d1.w + e1.w;
        // per-head (64-col) sum-of-squares: 8 lanes per head
        float ss = 0.f;
        #pragma unroll
        for (int j = 0; j < 8; ++j) ss = fmaf(v[j], v[j], ss);
        ss += __shfl_xor(ss, 1); ss += __shfl_xor(ss, 2); ss += __shfl_xor(ss, 4);
        float sc = rsqrtf(ss * (1.0f / 64.0f) + 1e-5f);
        float gg[8] = {g0.x, g0.y, g0.z, g0.w, g1.x, g1.y, g1.z, g1.w};
        float o_[8];
        #pragma unroll
        for (int j = 0; j < 8; ++j) o_[j] = v[j] * sc * gg[j];
        if (isQ) {
            float cf = Cp[row * 8 + (lane >> 3)] * 0.04419417382415922f;
            #pragma unroll
            for (int j = 0; j < 8; ++j) o_[j] *= cf;
            float* qp = Qpool + (row - NFULL) * 512 + c0;
            *(float4*)qp       = make_float4(o_[0], o_[1], o_[2], o_[3]);
            *(float4*)(qp + 4) = make_float4(o_[4], o_[5], o_[6], o_[7]);
            __hip_bfloat16 hb[8];
            #pragma unroll
            for (int j = 0; j < 8; ++j) hb[j] = __float2bfloat16(o_[j]);
            *(short8*)(Qh + row * 512 + c0) = *(const short8*)hb;
        } else {
            float* kp = Kn + row * 512 + c0;
            *(float4*)kp       = make_float4(o_[0], o_[1], o_[2], o_[3]);
            *(float4*)(kp + 4) = make_float4(o_[4], o_[5], o_[6], o_[7]);
            __hip_bfloat16 hb[8];
            #pragma unroll
            for (int j = 0; j < 8; ++j) hb[j] = __float2bfloat16(o_[j]);
            *(short8*)(Kh + row * 512 + c0) = *(const short8*)hb;
            float rs = 0.f;
            #pragma unroll
            for (int j = 0; j < 8; ++j) rs = fmaf(o_[j], o_[j], rs);
            #pragma unroll
            for (int o = 32; o > 0; o >>= 1) rs += __shfl_xor(rs, o);
            float* wsum = (float*)smraw;
            if (lane == 0) wsum[w] = rs;
            __syncthreads();
            if (tid == 0) {
                float m01 = fmaxf(wsum[0], wsum[1]);
                float m23 = fmaxf(wsum[2], wsum[3]);
                atomicMax(Kmax2i, __float_as_uint(fmaxf(m01, m23)));
            }
        }
    }
}

// ==== logits over all 5120 tokens ==========================================
// r13: 256x256 tile, BK=64, 512 threads (8 waves, 2m x 4n), SINGLE-buffered
// 64 KB LDS -> 2 blocks/CU resident (r12's 128 KB forced 1 block/CU: no
// cross-block drain hiding + 320-vs-256 grid quantization ate the 2x byte
// cut).  All 320 blocks co-resident in one round; the second block per CU
// fills the other's vmcnt(0) barrier drains (m114 mechanism).  Fragment
// mapping + epilogue identical to r12 (correctness-validated).
__global__ __launch_bounds__(512) void logits_full_k(
    const __hip_bfloat16* __restrict__ Qh, const __hip_bfloat16* __restrict__ Kh,
    u64* __restrict__ packed, __hip_bfloat16* __restrict__ Lp) {
    __shared__ __hip_bfloat16 As[256 * 64];   // 32 KB
    __shared__ __hip_bfloat16 Bs[256 * 64];   // 32 KB
    int tid = threadIdx.x;
    int mIdx = blockIdx.x, nIdx = blockIdx.y;  // (20, 16)
    int mB = mIdx * 256, nB = nIdx * 256;
    int lane = tid & 63, w = tid >> 6;         // w 0..7
    int wy = w >> 2, wx = w & 3;               // wy: m-half (128), wx: n-quarter (64)
    int lm = lane & 15, quad = lane >> 4;
    int lr8 = lane >> 3;
    int kcs = (lane & 7) ^ lr8;                // XOR-swizzled source col-chunk
    int rS = w * 32 + lr8;                     // 8 waves x 32 rows = 256
    const __hip_bfloat16* Ag = Qh + (mB + rS) * 512 + kcs * 8;
    const __hip_bfloat16* Bg = Kh + (nB + rS) * 512 + kcs * 8;
    int ldso = (w * 32) * 64 + lane * 8;
    f4 acc[8][4];
    #pragma unroll
    for (int i = 0; i < 8; ++i)
        #pragma unroll
        for (int j = 0; j < 4; ++j) acc[i][j] = f4{0.f, 0.f, 0.f, 0.f};
    int aswz = lm & 7;
    for (int kt = 0; kt < 8; ++kt) {
        __syncthreads();
        #pragma unroll
        for (int i = 0; i < 4; ++i) {
            gl_lds16(Ag + kt * 64 + i * 8 * 512, As + ldso + i * 8 * 64);
            gl_lds16(Bg + kt * 64 + i * 8 * 512, Bs + ldso + i * 8 * 64);
        }
        __syncthreads();
        #pragma unroll
        for (int s = 0; s < 2; ++s) {
            short8 aF[8], bF[4];
            int slot = ((s * 4 + quad) ^ aswz) << 3;
            #pragma unroll
            for (int mt = 0; mt < 8; ++mt)
                aF[mt] = *(const short8*)(As + (wy * 128 + mt * 16 + lm) * 64 + slot);
            #pragma unroll
            for (int nt = 0; nt < 4; ++nt)
                bF[nt] = *(const short8*)(Bs + (wx * 64 + nt * 16 + lm) * 64 + slot);
            #pragma unroll
            for (int mt = 0; mt < 8; ++mt)
                #pragma unroll
                for (int nt = 0; nt < 4; ++nt)
                    acc[mt][nt] = MFMA16(aF[mt], bF[nt], acc[mt][nt]);
        }
    }
    if (mIdx < 16) {
        // full-token rows: packed atomic argmax
        #pragma unroll
        for (int mt = 0; mt < 8; ++mt)
            #pragma unroll
            for (int reg = 0; reg < 4; ++reg) {
                float bv = -FLT_MAX; int bi = 0;
                #pragma unroll
                for (int nt = 0; nt < 4; ++nt) {
                    float v = acc[mt][nt][reg];
                    int n = nB + wx * 64 + nt * 16 + lm;
                    if (v > bv) { bv = v; bi = n; }
                }
                #pragma unroll
                for (int off = 1; off < 16; off <<= 1) {
                    float ov = __shfl_xor(bv, off);
                    int oi = __shfl_xor(bi, off);
                    if (ov > bv || (ov == bv && oi < bi)) { bv = ov; bi = oi; }
                }
                if (lm == 0) {
                    unsigned ub = __float_as_uint(bv);
                    ub = (ub & 0x80000000u) ? ~ub : (ub | 0x80000000u);
                    u64 key = ((u64)ub << 32) | (u64)(0xFFFFFFFFu - (unsigned)bi);
                    int tok = mB + wy * 128 + mt * 16 + quad * 4 + reg;
                    atomicMax(&packed[tok], key);
                }
            }
    } else {
        // pooled rows: bf16 logit rows for candidate rescore
        #pragma unroll
        for (int mt = 0; mt < 8; ++mt)
            #pragma unroll
            for (int reg = 0; reg < 4; ++reg) {
                int tok = mB + wy * 128 + mt * 16 + quad * 4 + reg;
                long long base = (long long)(tok - NFULL) * 4096;
                #pragma unroll
                for (int nt = 0; nt < 4; ++nt)
                    Lp[base + nB + wx * 64 + nt * 16 + lm] =
                        __float2bfloat16(acc[mt][nt][reg]);
            }
    }
}

// ======================= tail: rescore | hist+perplexity ===================
__global__ __launch_bounds__(256) void tail_k(
    const float* __restrict__ Qpool, const float* __restrict__ Kn,
    const __hip_bfloat16* __restrict__ Lp, const unsigned int* __restrict__ Kmax2i,
    const u64* __restrict__ packed, int* __restrict__ codeP,
    float* __restrict__ outPpl) {
    __shared__ int cnt[4096];
    __shared__ float red[4];
    int tid = threadIdx.x;
    if (blockIdx.x < 256) {
        int wid = tid >> 6, lane = tid & 63;
        int tok = blockIdx.x * 4 + wid;
        const float* q = Qpool + tok * 512;
        float4 q0 = *(const float4*)(q + lane * 8);
        float4 q1 = *(const float4*)(q + lane * 8 + 4);
        float qs = q0.x * q0.x + q0.y * q0.y + q0.z * q0.z + q0.w * q0.w +
                   q1.x * q1.x + q1.y * q1.y + q1.z * q1.z + q1.w * q1.w;
        #pragma unroll
        for (int o = 32; o > 0; o >>= 1) qs += __shfl_xor(qs, o);
        float delta = 0.0078125f * sqrtf(qs) * sqrtf(__uint_as_float(*Kmax2i));
        const __hip_bfloat16* row = Lp + (long long)tok * 4096;
        float mx = -FLT_MAX;
        for (int c = 0; c < 64; ++c)
            mx = fmaxf(mx, __bfloat162float(row[c * 64 + lane]));
        #pragma unroll
        for (int o = 32; o > 0; o >>= 1) mx = fmaxf(mx, __shfl_xor(mx, o));
        float thr = mx - delta;
        float bv = -FLT_MAX; int bi = 0;
        for (int c = 0; c < 64; ++c) {
            float v = __bfloat162float(row[c * 64 + lane]);
            u64 mask = __ballot(v >= thr);
            while (mask) {
                int l = __ffsll((long long)mask) - 1;
                mask &= mask - 1;
                int n = c * 64 + l;
                const float* k = Kn + n * 512;
                float4 k0 = *(const float4*)(k + lane * 8);
                float4 k1 = *(const float4*)(k + lane * 8 + 4);
                float d = q0.x * k0.x;
                d = fmaf(q0.y, k0.y, d); d = fmaf(q0.z, k0.z, d); d = fmaf(q0.w, k0.w, d);
                d = fmaf(q1.x, k1.x, d); d = fmaf(q1.y, k1.y, d);
                d = fmaf(q1.z, k1.z, d); d = fmaf(q1.w, k1.w, d);
                #pragma unroll
                for (int o = 32; o > 0; o >>= 1) d += __shfl_xor(d, o);
                if (d > bv) { bv = d; bi = n; }   // ascending n => first-max wins
            }
        }
        if (lane == 0) codeP[tok] = bi;
    } else {
        for (int i = tid; i < 4096; i += 256) cnt[i] = 0;
        __syncthreads();
        for (int i = tid; i < 4096; i += 256) {
            int bi = (int)(0xFFFFFFFFu - (unsigned)(packed[i] & 0xFFFFFFFFu));
            atomicAdd(&cnt[bi], 1);
        }
        __syncthreads();
        float s = 0.f;
        for (int i = tid; i < 4096; i += 256) {
            float p = (float)cnt[i] * (1.0f / 4096.0f);
            s += p * logf(p + 1e-7f);
        }
        #pragma unroll
        for (int o = 32; o > 0; o >>= 1) s += __shfl_xor(s, o);
        if ((tid & 63) == 0) red[tid >> 6] = s;
        __syncthreads();
        if (tid == 0)
            outPpl[0] = expf(-(red[0] + red[1] + red[2] + red[3]));
    }
}

// ======================= z_hat: wave per (b, j) ============================
__global__ void zhat_k(const float* __restrict__ Vv, const int* __restrict__ codeP,
                       float* __restrict__ out) {
    int w = (blockIdx.x << 2) + (threadIdx.x >> 6);   // 0..1023
    int lane = threadIdx.x & 63;
    int b = w >> 8, j = w & 255;
    const int* cb = codeP + (b << 8);
    const float* rm = Vv + cb[max(j - 1, 0)] * 512;
    const float* r0 = Vv + cb[j] * 512;
    const float* rp = Vv + cb[min(j + 1, 255)] * 512;
    #pragma unroll
    for (int i = 0; i < 8; ++i) {
        int c = i * 64 + lane;
        float vm = rm[c], v0 = r0[c], vp = rp[c];
        float4 o;
        o.x = 0.375f * vm + 0.625f * v0;
        o.y = 0.125f * vm + 0.875f * v0;
        o.z = 0.875f * v0 + 0.125f * vp;
        o.w = 0.625f * v0 + 0.375f * vp;
        *(float4*)&out[(((b << 9) + c) << 10) + (j << 2)] = o;
    }
}

extern "C" void kernel_launch(void* const* d_in, const int* in_sizes, int n_in,
                              void* d_out, int out_size, void* d_ws, size_t ws_size,
                              hipStream_t stream) {
    const float* z   = (const float*)d_in[0];
    const float* cbk = (const float*)d_in[2];
    const float* Wq  = (const float*)d_in[3];
    const float* bq  = (const float*)d_in[4];
    const float* Wk  = (const float*)d_in[5];
    const float* bk  = (const float*)d_in[6];
    const float* Wv  = (const float*)d_in[7];
    const float* bv  = (const float*)d_in[8];
    const float* Wp  = (const float*)d_in[9];
    const float* bp  = (const float*)d_in[10];
    const float* gq  = (const float*)d_in[11];
    const float* gk  = (const float*)d_in[12];
    float* out = (float*)d_out;

    // ---- workspace layout ----
    float* X      = (float*)d_ws;            // 5120*512 (only pooled rows used)
    float* Qpool  = X + 5120 * 512;          // 1024*512
    float* Kn     = Qpool + 1024 * 512;      // 4096*512
    float* Vb     = Kn + 4096 * 512;         // 4096*512
    float* Cp     = Vb + 4096 * 512;         // 5120*8
    float* P0     = Cp + 5120 * 8;           // 5120*512 (aliased by Lp later)
    float* P1     = P0 + 5120 * 512;         // 5120*512
    u64*   packed = (u64*)(P1 + 5120 * 512); // 4096
    unsigned int* Kmax2i = (unsigned int*)(packed + 4096);  // 4
    int*   codeP  = (int*)(Kmax2i + 4);      // 1024
    __hip_bfloat16* Qh  = (__hip_bfloat16*)(codeP + 1024);  // 5120*512
    __hip_bfloat16* Kh  = Qh + 5120 * 512;   // 4096*512
    __hip_bfloat16* Xh  = Kh + 4096 * 512;   // 4096*512
    __hip_bfloat16* cbh = Xh + 4096 * 512;   // 4096*512
    __hip_bfloat16* WqT = cbh + 4096 * 512;  // 512*512
    __hip_bfloat16* WvT = WqT + 512 * 512;   // 512*512
    __hip_bfloat16* Lp  = (__hip_bfloat16*)P0;  // alias: 1024*4096 bf16

    prep_k<<<4624, 256, 0, stream>>>(z, cbk, Wq, Wv, X, Xh, cbh, WqT, WvT,
                                     packed, Kmax2i);
    mid1_k<<<1920, 256, 0, stream>>>(Xh, cbk, X + 4096 * 512, Wk, Wq, Wp, bp,
                                     P0, P1, Cp);
    mid2_k<<<1536, 256, 0, stream>>>(Xh, WqT, cbh, WvT, P0, P1, bk, bq, gk, gq,
                                     Cp, bv, Qh, Vb, Kn, Kh, Qpool, Kmax2i);
    logits_full_k<<<dim3(20, 16), 512, 0, stream>>>(Qh, Kh, packed, Lp);
    tail_k<<<257, 256, 0, stream>>>(Qpool, Kn, Lp, Kmax2i, packed, codeP,
                                    out + 4 * 512 * 1024);
    zhat_k<<<256, 256, 0, stream>>>(Vb, codeP, out);
}

// Round 5
// 232.923 us; speedup vs baseline: 1.0705x; 1.0705x over previous
//
#include <hip/hip_runtime.h>
#include <hip/hip_bf16.h>
#include <cfloat>
#include <math.h>

#define NFULL 4096
#define NPOOL 1024
#define NTOK  5120
#define VDIM  4096

typedef __attribute__((ext_vector_type(8))) short short8;   // 8 bf16 (4 VGPR)
typedef __attribute__((ext_vector_type(4))) float f4;       // MFMA acc
typedef unsigned long long u64;

#define MFMA16(a,b,c) __builtin_amdgcn_mfma_f32_16x16x32_bf16((a),(b),(c),0,0,0)

static __device__ __forceinline__ void gl_lds16(const void* g, void* l) {
    __builtin_amdgcn_global_load_lds(
        (const __attribute__((address_space(1))) unsigned int*)g,
        (__attribute__((address_space(3))) unsigned int*)l, 16, 0, 0);
}

// ==== bf16 MFMA 128x128 core, BK=64, XOR-swizzled LDS (r4-verified) ========
// Requires As, Bs to span 128*64 bf16 (16 KB) EACH.  Single-buffered,
// 2 barriers per K-step.  Used by mid2_k (proven; limits blast radius).
#define BGEMM3_CORE(AM, Bt)                                                    \
    int lane = tid & 63, w = tid >> 6, wy = w >> 1, wx = w & 1;                \
    int lm = lane & 15, quad = lane >> 4;                                      \
    int lr8 = lane >> 3;                                                       \
    int kcs = (lane & 7) ^ lr8;                                                \
    int rS = w * 32 + lr8;                                                     \
    const __hip_bfloat16* Ag = (AM) + (mB + rS) * 512 + kcs * 8;               \
    const __hip_bfloat16* Bg = (Bt) + (nB + rS) * 512 + kcs * 8;               \
    __hip_bfloat16* Al = As + (w * 32) * 64 + lane * 8;                        \
    __hip_bfloat16* Bl = Bs + (w * 32) * 64 + lane * 8;                        \
    f4 acc[4][4];                                                              \
    _Pragma("unroll") for (int i = 0; i < 4; ++i)                              \
        _Pragma("unroll") for (int j = 0; j < 4; ++j)                          \
            acc[i][j] = f4{0.f, 0.f, 0.f, 0.f};                                \
    int aswz = lm & 7;                                                         \
    for (int kt = 0; kt < 8; ++kt) {                                           \
        __syncthreads();                                                       \
        _Pragma("unroll") for (int i = 0; i < 4; ++i) {                        \
            gl_lds16(Ag + kt * 64 + i * 8 * 512, Al + i * 8 * 64);             \
            gl_lds16(Bg + kt * 64 + i * 8 * 512, Bl + i * 8 * 64);             \
        }                                                                      \
        __syncthreads();                                                       \
        _Pragma("unroll") for (int s = 0; s < 2; ++s) {                        \
            short8 aF[4], bF[4];                                               \
            int slot = ((s * 4 + quad) ^ aswz) << 3;                           \
            _Pragma("unroll") for (int mt = 0; mt < 4; ++mt)                   \
                aF[mt] = *(const short8*)(As + (wy * 64 + mt * 16 + lm) * 64 + slot); \
            _Pragma("unroll") for (int nt = 0; nt < 4; ++nt)                   \
                bF[nt] = *(const short8*)(Bs + (wx * 64 + nt * 16 + lm) * 64 + slot); \
            _Pragma("unroll") for (int mt = 0; mt < 4; ++mt)                   \
                _Pragma("unroll") for (int nt = 0; nt < 4; ++nt)               \
                    acc[mt][nt] = MFMA16(aF[mt], bF[nt], acc[mt][nt]);         \
        }                                                                      \
    }

// ======================= prep: transposes + casts + zero-init ==============
__global__ void prep_k(const float* __restrict__ z, const float* __restrict__ cbk,
                       const float* __restrict__ Wq, const float* __restrict__ Wv,
                       float* __restrict__ X, __hip_bfloat16* __restrict__ Xh,
                       __hip_bfloat16* __restrict__ cbh,
                       __hip_bfloat16* __restrict__ WqT, __hip_bfloat16* __restrict__ WvT,
                       u64* __restrict__ packed, unsigned int* __restrict__ Kmax2i) {
    __shared__ float smem[33 * 32];
    int bx = blockIdx.x;
    if (bx < 2048) {
        float (*tile)[33] = (float(*)[33])smem;
        int t0 = (bx & 31) * 32, c0 = ((bx >> 5) & 15) * 32, b = bx >> 9;
        int tx = threadIdx.x & 31, ty = threadIdx.x >> 5;
        #pragma unroll
        for (int i = 0; i < 4; ++i) {
            int c = ty + i * 8;
            tile[c][tx] = z[((b << 9) + c0 + c) * 1024 + t0 + tx];
        }
        __syncthreads();
        #pragma unroll
        for (int i = 0; i < 4; ++i) {
            int tl = ty + i * 8;
            int tok = (b << 10) + t0 + tl;
            Xh[tok * 512 + c0 + tx] = __float2bfloat16(tile[tx][tl]);
        }
        float m = 0.25f * (tile[tx][ty * 4] + tile[tx][ty * 4 + 1] +
                           tile[tx][ty * 4 + 2] + tile[tx][ty * 4 + 3]);
        int tq = (t0 >> 2) + ty;
        X[(NFULL + (b << 8) + tq) * 512 + c0 + tx] = m;
    } else if (bx < 4096) {
        int i0 = (bx - 2048) * 1024 + threadIdx.x * 4;
        float4 v = *(const float4*)(cbk + i0);
        __hip_bfloat16* d = cbh + i0;
        d[0] = __float2bfloat16(v.x); d[1] = __float2bfloat16(v.y);
        d[2] = __float2bfloat16(v.z); d[3] = __float2bfloat16(v.w);
    } else if (bx < 4608) {
        int lin = bx - 4096;
        const float* W = (lin >> 8) ? Wv : Wq;
        __hip_bfloat16* WT = (lin >> 8) ? WvT : WqT;
        float (*t)[33] = (float(*)[33])smem;
        int bk = ((lin >> 4) & 15) * 32, bn = (lin & 15) * 32;
        int lx = threadIdx.x & 31, ly = threadIdx.x >> 5;
        #pragma unroll
        for (int i = 0; i < 4; ++i) {
            int r = ly * 4 + i;
            t[r][lx] = W[(bk + r) * 512 + bn + lx];
        }
        __syncthreads();
        #pragma unroll
        for (int i = 0; i < 4; ++i) {
            int r = ly * 4 + i;
            WT[(bn + r) * 512 + bk + lx] = __float2bfloat16(t[lx][r]);
        }
    } else {
        int i = (bx - 4608) * 256 + threadIdx.x;     // 0..4095
        packed[i] = 0ull;
        if (bx == 4608 && threadIdx.x == 0) Kmax2i[0] = 0u;
    }
}

// ======================= mid1: fp32 proj | pool-c (both depend on prep) ====
__global__ __launch_bounds__(256) void mid1_k(
    const __hip_bfloat16* __restrict__ Xh,
    const float* __restrict__ cbk, const float* __restrict__ Xp,
    const float* __restrict__ Wk, const float* __restrict__ Wq,
    const float* __restrict__ Wp, const float* __restrict__ bp,
    float* __restrict__ P0, float* __restrict__ P1, float* __restrict__ Cp) {
    __shared__ __align__(16) char smraw[16640];
    int bx = blockIdx.x, tid = threadIdx.x;
    if (bx < 640) {
        // ---------------- fp32 split-K projection ---------------------------
        float (*As2)[68]  = (float(*)[68])smraw;
        float (*Bs2)[132] = (float(*)[132])(smraw + 16 * 68 * 4);
        int kz = bx >= 320;
        int rem = bx - kz * 320;
        int mB = (rem % 80) * 64, nB = (rem / 80) * 128, kOff = kz * 256;
        const float *A, *B;
        if (mB < NFULL) { A = cbk + mB * 512; B = Wk; }
        else            { A = Xp + (mB - NFULL) * 512; B = Wq; }
        int ty = tid >> 4, tx = tid & 15;
        int arow = tid >> 2, achk = tid & 3;
        int brow = tid >> 4, bcol = (tid & 15) * 4;
        const float* Ap = A + arow * 512 + kOff + achk * 4;
        const float* Bp = B + (kOff + brow) * 512 + nB + bcol;
        float acc[4][8] = {};
        for (int kt = 0; kt < 16; ++kt) {
            float4 a  = *(const float4*)(Ap + kt * 16);
            float4 b0 = *(const float4*)(Bp + kt * 16 * 512);
            float4 b1 = *(const float4*)(Bp + kt * 16 * 512 + 64);
            __syncthreads();
            As2[achk * 4 + 0][arow] = a.x; As2[achk * 4 + 1][arow] = a.y;
            As2[achk * 4 + 2][arow] = a.z; As2[achk * 4 + 3][arow] = a.w;
            *(float4*)&Bs2[brow][bcol]      = b0;
            *(float4*)&Bs2[brow][bcol + 64] = b1;
            __syncthreads();
            #pragma unroll
            for (int kk = 0; kk < 16; ++kk) {
                float4 av  = *(const float4*)&As2[kk][ty * 4];
                float4 bv0 = *(const float4*)&Bs2[kk][tx * 4];
                float4 bv1 = *(const float4*)&Bs2[kk][64 + tx * 4];
                float a4[4] = {av.x, av.y, av.z, av.w};
                float b8[8] = {bv0.x, bv0.y, bv0.z, bv0.w, bv1.x, bv1.y, bv1.z, bv1.w};
                #pragma unroll
                for (int i = 0; i < 4; ++i)
                    #pragma unroll
                    for (int j = 0; j < 8; ++j)
                        acc[i][j] = fmaf(a4[i], b8[j], acc[i][j]);
            }
        }
        float* P = kz ? P1 : P0;
        #pragma unroll
        for (int i = 0; i < 4; ++i) {
            int row = mB + ty * 4 + i;
            float4 r0, r1;
            r0.x = acc[i][0]; r0.y = acc[i][1]; r0.z = acc[i][2]; r0.w = acc[i][3];
            r1.x = acc[i][4]; r1.y = acc[i][5]; r1.z = acc[i][6]; r1.w = acc[i][7];
            *(float4*)&P[row * 512 + nB + tx * 4]      = r0;
            *(float4*)&P[row * 512 + nB + 64 + tx * 4] = r1;
        }
    } else {
        // ---------------- head-pool weights Cp ------------------------------
        float* Wl = (float*)smraw;             // 4160 floats: lane stride 65
        for (int i = tid; i < 4096; i += 256) Wl[i + (i >> 6)] = Wp[i];
        __syncthreads();
        int w = tid >> 6, lane = tid & 63;
        int tok = (bx - 640) * 4 + w;          // 0..5119
        float x[8];
        if (tok < NFULL) {
            short8 xv = *(const short8*)(Xh + tok * 512 + lane * 8);
            #pragma unroll
            for (int j = 0; j < 8; ++j)
                x[j] = __uint_as_float(((unsigned)(unsigned short)xv[j]) << 16);
        } else {
            const float* xp = Xp + (tok - NFULL) * 512 + lane * 8;
            float4 a = *(const float4*)xp, b = *(const float4*)(xp + 4);
            x[0] = a.x; x[1] = a.y; x[2] = a.z; x[3] = a.w;
            x[4] = b.x; x[5] = b.y; x[6] = b.z; x[7] = b.w;
        }
        float s[8] = {};
        int base = lane * 65;
        #pragma unroll
        for (int j = 0; j < 8; ++j)
            #pragma unroll
            for (int h = 0; h < 8; ++h)
                s[h] = fmaf(x[j], Wl[base + j * 8 + h], s[h]);
        #pragma unroll
        for (int h = 0; h < 8; ++h)
            #pragma unroll
            for (int o = 32; o > 0; o >>= 1) s[h] += __shfl_xor(s[h], o);
        if (lane == 0) {
            #pragma unroll
            for (int h = 0; h < 8; ++h) Cp[tok * 8 + h] = s[h] + bp[h];
        }
    }
}

// ======================= mid2: bf16 bgemms | split-K norm-finish ===========
// [0,256): MFMA GEMMs (Qproj+norm reads Cp - ordered after mid1; Vproj).
// [256,1536): norm-finish, WAVE-PER-ROW, 4 rows/block.
// NOTE: smraw MUST be 32768 B — BGEMM3_CORE uses As (16 KB) + Bs (16 KB).
__global__ __launch_bounds__(256) void mid2_k(
    const __hip_bfloat16* __restrict__ Xh, const __hip_bfloat16* __restrict__ WqT,
    const __hip_bfloat16* __restrict__ cbh, const __hip_bfloat16* __restrict__ WvT,
    const float* __restrict__ P0, const float* __restrict__ P1,
    const float* __restrict__ bk, const float* __restrict__ bq,
    const float* __restrict__ gk, const float* __restrict__ gq,
    const float* __restrict__ Cp, const float* __restrict__ bvv,
    __hip_bfloat16* __restrict__ Qh, float* __restrict__ Vb,
    float* __restrict__ Kn, __hip_bfloat16* __restrict__ Kh,
    float* __restrict__ Qpool, unsigned int* __restrict__ Kmax2i) {
    __shared__ __align__(16) char smraw[32768];
    int bx = blockIdx.x, tid = threadIdx.x;
    if (bx < 256) {
        int part = bx >> 7, rem = bx & 127;
        int mB = (rem & 31) * 128, nB = (rem >> 5) * 128;
        const __hip_bfloat16* AM = part ? cbh : Xh;
        const __hip_bfloat16* Bt = part ? WvT : WqT;
        __hip_bfloat16* As = (__hip_bfloat16*)smraw;
        __hip_bfloat16* Bs = As + 128 * 64;
        BGEMM3_CORE(AM, Bt)
        if (part == 0) {
            int h = (rem >> 5) * 2 + wx;
            float bb[4], gg[4];
            #pragma unroll
            for (int nt = 0; nt < 4; ++nt) {
                bb[nt] = bq[h * 64 + nt * 16 + lm];
                gg[nt] = gq[nt * 16 + lm];
            }
            #pragma unroll
            for (int mt = 0; mt < 4; ++mt)
                #pragma unroll
                for (int reg = 0; reg < 4; ++reg) {
                    int tok = mB + wy * 64 + mt * 16 + quad * 4 + reg;
                    float vv[4], ss = 0.f;
                    #pragma unroll
                    for (int nt = 0; nt < 4; ++nt) {
                        vv[nt] = acc[mt][nt][reg] + bb[nt];
                        ss = fmaf(vv[nt], vv[nt], ss);
                    }
                    #pragma unroll
                    for (int off = 1; off < 16; off <<= 1) ss += __shfl_xor(ss, off);
                    float sc = rsqrtf(ss * (1.0f / 64.0f) + 1e-5f) *
                               Cp[tok * 8 + h] * 0.04419417382415922f;  // 1/(8*sqrt8)
                    #pragma unroll
                    for (int nt = 0; nt < 4; ++nt)
                        Qh[tok * 512 + h * 64 + nt * 16 + lm] =
                            __float2bfloat16(vv[nt] * sc * gg[nt]);
                }
        } else {
            float bb[4];
            #pragma unroll
            for (int nt = 0; nt < 4; ++nt) bb[nt] = bvv[nB + wx * 64 + nt * 16 + lm];
            #pragma unroll
            for (int mt = 0; mt < 4; ++mt)
                #pragma unroll
                for (int reg = 0; reg < 4; ++reg) {
                    int m = mB + wy * 64 + mt * 16 + quad * 4 + reg;
                    #pragma unroll
                    for (int nt = 0; nt < 4; ++nt)
                        Vb[m * 512 + nB + wx * 64 + nt * 16 + lm] =
                            acc[mt][nt][reg] + bb[nt];
                }
        }
    } else {
        // ---------------- split-K reduce + rmsnorm (wave-per-row) -----------
        int w = tid >> 6, lane = tid & 63;
        int row = (bx - 256) * 4 + w;      // 0..5119
        bool isQ = row >= NFULL;
        const float* bias = isQ ? bq : bk;
        const float* g = isQ ? gq : gk;
        int c0 = lane * 8;                 // 8 contiguous cols per lane
        const float* p0 = P0 + row * 512 + c0;
        const float* p1 = P1 + row * 512 + c0;
        float4 a0 = *(const float4*)p0,  a1 = *(const float4*)(p0 + 4);
        float4 d0 = *(const float4*)p1,  d1 = *(const float4*)(p1 + 4);
        float4 e0 = *(const float4*)(bias + c0), e1 = *(const float4*)(bias + c0 + 4);
        int gi = (lane & 7) * 8;
        float4 g0 = *(const float4*)(g + gi), g1 = *(const float4*)(g + gi + 4);
        float v[8];
        v[0] = a0.x + d0.x + e0.x; v[1] = a0.y + d0.y + e0.y;
        v[2] = a0.z + d0.z + e0.z; v[3] = a0.w + d0.w + e0.w;
        v[4] = a1.x + d1.x + e1.x; v[5] = a1.y + d1.y + e1.y;
        v[6] = a1.z + d1.z + e1.z; v[7] = a1.w + d1.w + e1.w;
        // per-head (64-col) sum-of-squares: 8 lanes per head
        float ss = 0.f;
        #pragma unroll
        for (int j = 0; j < 8; ++j) ss = fmaf(v[j], v[j], ss);
        ss += __shfl_xor(ss, 1); ss += __shfl_xor(ss, 2); ss += __shfl_xor(ss, 4);
        float sc = rsqrtf(ss * (1.0f / 64.0f) + 1e-5f);
        float gg[8] = {g0.x, g0.y, g0.z, g0.w, g1.x, g1.y, g1.z, g1.w};
        float o_[8];
        #pragma unroll
        for (int j = 0; j < 8; ++j) o_[j] = v[j] * sc * gg[j];
        if (isQ) {
            float cf = Cp[row * 8 + (lane >> 3)] * 0.04419417382415922f;
            #pragma unroll
            for (int j = 0; j < 8; ++j) o_[j] *= cf;
            float* qp = Qpool + (row - NFULL) * 512 + c0;
            *(float4*)qp       = make_float4(o_[0], o_[1], o_[2], o_[3]);
            *(float4*)(qp + 4) = make_float4(o_[4], o_[5], o_[6], o_[7]);
            __hip_bfloat16 hb[8];
            #pragma unroll
            for (int j = 0; j < 8; ++j) hb[j] = __float2bfloat16(o_[j]);
            *(short8*)(Qh + row * 512 + c0) = *(const short8*)hb;
        } else {
            float* kp = Kn + row * 512 + c0;
            *(float4*)kp       = make_float4(o_[0], o_[1], o_[2], o_[3]);
            *(float4*)(kp + 4) = make_float4(o_[4], o_[5], o_[6], o_[7]);
            __hip_bfloat16 hb[8];
            #pragma unroll
            for (int j = 0; j < 8; ++j) hb[j] = __float2bfloat16(o_[j]);
            *(short8*)(Kh + row * 512 + c0) = *(const short8*)hb;
            float rs = 0.f;
            #pragma unroll
            for (int j = 0; j < 8; ++j) rs = fmaf(o_[j], o_[j], rs);
            #pragma unroll
            for (int o = 32; o > 0; o >>= 1) rs += __shfl_xor(rs, o);
            float* wsum = (float*)smraw;
            if (lane == 0) wsum[w] = rs;
            __syncthreads();
            if (tid == 0) {
                float m01 = fmaxf(wsum[0], wsum[1]);
                float m23 = fmaxf(wsum[2], wsum[3]);
                atomicMax(Kmax2i, __float_as_uint(fmaxf(m01, m23)));
            }
        }
    }
}

// ==== logits over all 5120 tokens ==========================================
// r14: 128^2 db tile (proven-best geometry, 1280 blocks, 2 blocks/CU) with
// COUNTED-vmcnt pipeline (catalog T4).  The r10 double-buffer was defeated
// by __syncthreads()'s implicit vmcnt(0): it drained the prefetch it had
// just issued.  New K-step schedule (never drains in main loop):
//   barrier1 (buffer-reuse guard: all waves done reading next-buf)
//   issue 8 gl_lds16 -> next-buf
//   s_waitcnt vmcnt(8)   // wait ONLY for current-buf loads; new 8 in flight
//   barrier2             // everyone's current-buf loads landed
//   sched_barrier(0); ds_read + MFMA on current-buf
// Race analysis in commit notes; "memory" clobber + sched_barrier(0) keep
// hipcc from hoisting LDS reads above the wait (guide rule #18).
__global__ __launch_bounds__(256) void logits_full_k(
    const __hip_bfloat16* __restrict__ Qh, const __hip_bfloat16* __restrict__ Kh,
    u64* __restrict__ packed, __hip_bfloat16* __restrict__ Lp) {
    __shared__ __hip_bfloat16 As0[128 * 64];
    __shared__ __hip_bfloat16 Bs0[128 * 64];
    __shared__ __hip_bfloat16 As1[128 * 64];
    __shared__ __hip_bfloat16 Bs1[128 * 64];
    int tid = threadIdx.x;
    int mB = blockIdx.x * 128, nB = blockIdx.y * 128;
    int lane = tid & 63, w = tid >> 6, wy = w >> 1, wx = w & 1;
    int lm = lane & 15, quad = lane >> 4;
    int lr8 = lane >> 3;
    int kcs = (lane & 7) ^ lr8;
    int rS = w * 32 + lr8;
    const __hip_bfloat16* Ag = Qh + (mB + rS) * 512 + kcs * 8;
    const __hip_bfloat16* Bg = Kh + (nB + rS) * 512 + kcs * 8;
    int ldso = (w * 32) * 64 + lane * 8;
    f4 acc[4][4];
    #pragma unroll
    for (int i = 0; i < 4; ++i)
        #pragma unroll
        for (int j = 0; j < 4; ++j) acc[i][j] = f4{0.f, 0.f, 0.f, 0.f};
    int aswz = lm & 7;
    // prologue: stage kt=0 into buf0 (8 loads in flight)
    #pragma unroll
    for (int i = 0; i < 4; ++i) {
        gl_lds16(Ag + i * 8 * 512, As0 + ldso + i * 8 * 64);
        gl_lds16(Bg + i * 8 * 512, Bs0 + ldso + i * 8 * 64);
    }
    for (int kt = 0; kt < 8; ++kt) {
        __hip_bfloat16* Ac = (kt & 1) ? As1 : As0;
        __hip_bfloat16* Bc = (kt & 1) ? Bs1 : Bs0;
        // barrier1: all waves finished READING the buffer we are about to
        // overwrite (it was computed at kt-1, before each wave got here).
        __builtin_amdgcn_s_barrier();
        if (kt < 7) {
            __hip_bfloat16* An = (kt & 1) ? As0 : As1;
            __hip_bfloat16* Bn = (kt & 1) ? Bs0 : Bs1;
            #pragma unroll
            for (int i = 0; i < 4; ++i) {
                gl_lds16(Ag + (kt + 1) * 64 + i * 8 * 512, An + ldso + i * 8 * 64);
                gl_lds16(Bg + (kt + 1) * 64 + i * 8 * 512, Bn + ldso + i * 8 * 64);
            }
            // wait for THIS wave's current-buf loads (8 newest stay in flight)
            asm volatile("s_waitcnt vmcnt(8)" ::: "memory");
        } else {
            asm volatile("s_waitcnt vmcnt(0)" ::: "memory");
        }
        // barrier2: every wave's current-buf loads have landed.
        __builtin_amdgcn_s_barrier();
        __builtin_amdgcn_sched_barrier(0);
        #pragma unroll
        for (int s = 0; s < 2; ++s) {
            short8 aF[4], bF[4];
            int slot = ((s * 4 + quad) ^ aswz) << 3;
            #pragma unroll
            for (int mt = 0; mt < 4; ++mt)
                aF[mt] = *(const short8*)(Ac + (wy * 64 + mt * 16 + lm) * 64 + slot);
            #pragma unroll
            for (int nt = 0; nt < 4; ++nt)
                bF[nt] = *(const short8*)(Bc + (wx * 64 + nt * 16 + lm) * 64 + slot);
            #pragma unroll
            for (int mt = 0; mt < 4; ++mt)
                #pragma unroll
                for (int nt = 0; nt < 4; ++nt)
                    acc[mt][nt] = MFMA16(aF[mt], bF[nt], acc[mt][nt]);
        }
    }
    if (blockIdx.x < 32) {
        // full-token rows: packed atomic argmax
        #pragma unroll
        for (int mt = 0; mt < 4; ++mt)
            #pragma unroll
            for (int reg = 0; reg < 4; ++reg) {
                float bv = -FLT_MAX; int bi = 0;
                #pragma unroll
                for (int nt = 0; nt < 4; ++nt) {
                    float v = acc[mt][nt][reg];
                    int n = nB + wx * 64 + nt * 16 + lm;
                    if (v > bv) { bv = v; bi = n; }
                }
                #pragma unroll
                for (int off = 1; off < 16; off <<= 1) {
                    float ov = __shfl_xor(bv, off);
                    int oi = __shfl_xor(bi, off);
                    if (ov > bv || (ov == bv && oi < bi)) { bv = ov; bi = oi; }
                }
                if (lm == 0) {
                    unsigned ub = __float_as_uint(bv);
                    ub = (ub & 0x80000000u) ? ~ub : (ub | 0x80000000u);
                    u64 key = ((u64)ub << 32) | (u64)(0xFFFFFFFFu - (unsigned)bi);
                    int tok = mB + wy * 64 + mt * 16 + quad * 4 + reg;
                    atomicMax(&packed[tok], key);
                }
            }
    } else {
        // pooled rows: bf16 logit rows for candidate rescore
        #pragma unroll
        for (int mt = 0; mt < 4; ++mt)
            #pragma unroll
            for (int reg = 0; reg < 4; ++reg) {
                int tok = mB + wy * 64 + mt * 16 + quad * 4 + reg;
                long long base = (long long)(tok - NFULL) * 4096;
                #pragma unroll
                for (int nt = 0; nt < 4; ++nt)
                    Lp[base + nB + wx * 64 + nt * 16 + lm] =
                        __float2bfloat16(acc[mt][nt][reg]);
            }
    }
}

// ======================= tail: rescore | hist+perplexity ===================
__global__ __launch_bounds__(256) void tail_k(
    const float* __restrict__ Qpool, const float* __restrict__ Kn,
    const __hip_bfloat16* __restrict__ Lp, const unsigned int* __restrict__ Kmax2i,
    const u64* __restrict__ packed, int* __restrict__ codeP,
    float* __restrict__ outPpl) {
    __shared__ int cnt[4096];
    __shared__ float red[4];
    int tid = threadIdx.x;
    if (blockIdx.x < 256) {
        int wid = tid >> 6, lane = tid & 63;
        int tok = blockIdx.x * 4 + wid;
        const float* q = Qpool + tok * 512;
        float4 q0 = *(const float4*)(q + lane * 8);
        float4 q1 = *(const float4*)(q + lane * 8 + 4);
        float qs = q0.x * q0.x + q0.y * q0.y + q0.z * q0.z + q0.w * q0.w +
                   q1.x * q1.x + q1.y * q1.y + q1.z * q1.z + q1.w * q1.w;
        #pragma unroll
        for (int o = 32; o > 0; o >>= 1) qs += __shfl_xor(qs, o);
        float delta = 0.0078125f * sqrtf(qs) * sqrtf(__uint_as_float(*Kmax2i));
        const __hip_bfloat16* row = Lp + (long long)tok * 4096;
        float mx = -FLT_MAX;
        for (int c = 0; c < 64; ++c)
            mx = fmaxf(mx, __bfloat162float(row[c * 64 + lane]));
        #pragma unroll
        for (int o = 32; o > 0; o >>= 1) mx = fmaxf(mx, __shfl_xor(mx, o));
        float thr = mx - delta;
        float bv = -FLT_MAX; int bi = 0;
        for (int c = 0; c < 64; ++c) {
            float v = __bfloat162float(row[c * 64 + lane]);
            u64 mask = __ballot(v >= thr);
            while (mask) {
                int l = __ffsll((long long)mask) - 1;
                mask &= mask - 1;
                int n = c * 64 + l;
                const float* k = Kn + n * 512;
                float4 k0 = *(const float4*)(k + lane * 8);
                float4 k1 = *(const float4*)(k + lane * 8 + 4);
                float d = q0.x * k0.x;
                d = fmaf(q0.y, k0.y, d); d = fmaf(q0.z, k0.z, d); d = fmaf(q0.w, k0.w, d);
                d = fmaf(q1.x, k1.x, d); d = fmaf(q1.y, k1.y, d);
                d = fmaf(q1.z, k1.z, d); d = fmaf(q1.w, k1.w, d);
                #pragma unroll
                for (int o = 32; o > 0; o >>= 1) d += __shfl_xor(d, o);
                if (d > bv) { bv = d; bi = n; }   // ascending n => first-max wins
            }
        }
        if (lane == 0) codeP[tok] = bi;
    } else {
        for (int i = tid; i < 4096; i += 256) cnt[i] = 0;
        __syncthreads();
        for (int i = tid; i < 4096; i += 256) {
            int bi = (int)(0xFFFFFFFFu - (unsigned)(packed[i] & 0xFFFFFFFFu));
            atomicAdd(&cnt[bi], 1);
        }
        __syncthreads();
        float s = 0.f;
        for (int i = tid; i < 4096; i += 256) {
            float p = (float)cnt[i] * (1.0f / 4096.0f);
            s += p * logf(p + 1e-7f);
        }
        #pragma unroll
        for (int o = 32; o > 0; o >>= 1) s += __shfl_xor(s, o);
        if ((tid & 63) == 0) red[tid >> 6] = s;
        __syncthreads();
        if (tid == 0)
            outPpl[0] = expf(-(red[0] + red[1] + red[2] + red[3]));
    }
}

// ======================= z_hat: wave per (b, j) ============================
__global__ void zhat_k(const float* __restrict__ Vv, const int* __restrict__ codeP,
                       float* __restrict__ out) {
    int w = (blockIdx.x << 2) + (threadIdx.x >> 6);   // 0..1023
    int lane = threadIdx.x & 63;
    int b = w >> 8, j = w & 255;
    const int* cb = codeP + (b << 8);
    const float* rm = Vv + cb[max(j - 1, 0)] * 512;
    const float* r0 = Vv + cb[j] * 512;
    const float* rp = Vv + cb[min(j + 1, 255)] * 512;
    #pragma unroll
    for (int i = 0; i < 8; ++i) {
        int c = i * 64 + lane;
        float vm = rm[c], v0 = r0[c], vp = rp[c];
        float4 o;
        o.x = 0.375f * vm + 0.625f * v0;
        o.y = 0.125f * vm + 0.875f * v0;
        o.z = 0.875f * v0 + 0.125f * vp;
        o.w = 0.625f * v0 + 0.375f * vp;
        *(float4*)&out[(((b << 9) + c) << 10) + (j << 2)] = o;
    }
}

extern "C" void kernel_launch(void* const* d_in, const int* in_sizes, int n_in,
                              void* d_out, int out_size, void* d_ws, size_t ws_size,
                              hipStream_t stream) {
    const float* z   = (const float*)d_in[0];
    const float* cbk = (const float*)d_in[2];
    const float* Wq  = (const float*)d_in[3];
    const float* bq  = (const float*)d_in[4];
    const float* Wk  = (const float*)d_in[5];
    const float* bk  = (const float*)d_in[6];
    const float* Wv  = (const float*)d_in[7];
    const float* bv  = (const float*)d_in[8];
    const float* Wp  = (const float*)d_in[9];
    const float* bp  = (const float*)d_in[10];
    const float* gq  = (const float*)d_in[11];
    const float* gk  = (const float*)d_in[12];
    float* out = (float*)d_out;

    // ---- workspace layout ----
    float* X      = (float*)d_ws;            // 5120*512 (only pooled rows used)
    float* Qpool  = X + 5120 * 512;          // 1024*512
    float* Kn     = Qpool + 1024 * 512;      // 4096*512
    float* Vb     = Kn + 4096 * 512;         // 4096*512
    float* Cp     = Vb + 4096 * 512;         // 5120*8
    float* P0     = Cp + 5120 * 8;           // 5120*512 (aliased by Lp later)
    float* P1     = P0 + 5120 * 512;         // 5120*512
    u64*   packed = (u64*)(P1 + 5120 * 512); // 4096
    unsigned int* Kmax2i = (unsigned int*)(packed + 4096);  // 4
    int*   codeP  = (int*)(Kmax2i + 4);      // 1024
    __hip_bfloat16* Qh  = (__hip_bfloat16*)(codeP + 1024);  // 5120*512
    __hip_bfloat16* Kh  = Qh + 5120 * 512;   // 4096*512
    __hip_bfloat16* Xh  = Kh + 4096 * 512;   // 4096*512
    __hip_bfloat16* cbh = Xh + 4096 * 512;   // 4096*512
    __hip_bfloat16* WqT = cbh + 4096 * 512;  // 512*512
    __hip_bfloat16* WvT = WqT + 512 * 512;   // 512*512
    __hip_bfloat16* Lp  = (__hip_bfloat16*)P0;  // alias: 1024*4096 bf16

    prep_k<<<4624, 256, 0, stream>>>(z, cbk, Wq, Wv, X, Xh, cbh, WqT, WvT,
                                     packed, Kmax2i);
    mid1_k<<<1920, 256, 0, stream>>>(Xh, cbk, X + 4096 * 512, Wk, Wq, Wp, bp,
                                     P0, P1, Cp);
    mid2_k<<<1536, 256, 0, stream>>>(Xh, WqT, cbh, WvT, P0, P1, bk, bq, gk, gq,
                                     Cp, bv, Qh, Vb, Kn, Kh, Qpool, Kmax2i);
    logits_full_k<<<dim3(40, 32), 256, 0, stream>>>(Qh, Kh, packed, Lp);
    tail_k<<<257, 256, 0, stream>>>(Qpool, Kn, Lp, Kmax2i, packed, codeP,
                                    out + 4 * 512 * 1024);
    zhat_k<<<256, 256, 0, stream>>>(Vb, codeP, out);
}

// Round 6
// 229.838 us; speedup vs baseline: 1.0849x; 1.0134x over previous
//
#include <hip/hip_runtime.h>
#include <hip/hip_bf16.h>
#include <cfloat>
#include <math.h>

#define NFULL 4096
#define NPOOL 1024
#define NTOK  5120
#define VDIM  4096

typedef __attribute__((ext_vector_type(8))) short short8;   // 8 bf16 (4 VGPR)
typedef __attribute__((ext_vector_type(4))) float f4;       // MFMA acc
typedef unsigned long long u64;

#define MFMA16(a,b,c) __builtin_amdgcn_mfma_f32_16x16x32_bf16((a),(b),(c),0,0,0)

static __device__ __forceinline__ void gl_lds16(const void* g, void* l) {
    __builtin_amdgcn_global_load_lds(
        (const __attribute__((address_space(1))) unsigned int*)g,
        (__attribute__((address_space(3))) unsigned int*)l, 16, 0, 0);
}

// ==== bf16 MFMA 128x128 core, BK=64, XOR-swizzled LDS (r4-verified) ========
// Requires As, Bs to span 128*64 bf16 (16 KB) EACH.  Single-buffered,
// 2 barriers per K-step.  Used by mid2_k (proven; limits blast radius).
#define BGEMM3_CORE(AM, Bt)                                                    \
    int lane = tid & 63, w = tid >> 6, wy = w >> 1, wx = w & 1;                \
    int lm = lane & 15, quad = lane >> 4;                                      \
    int lr8 = lane >> 3;                                                       \
    int kcs = (lane & 7) ^ lr8;                                                \
    int rS = w * 32 + lr8;                                                     \
    const __hip_bfloat16* Ag = (AM) + (mB + rS) * 512 + kcs * 8;               \
    const __hip_bfloat16* Bg = (Bt) + (nB + rS) * 512 + kcs * 8;               \
    __hip_bfloat16* Al = As + (w * 32) * 64 + lane * 8;                        \
    __hip_bfloat16* Bl = Bs + (w * 32) * 64 + lane * 8;                        \
    f4 acc[4][4];                                                              \
    _Pragma("unroll") for (int i = 0; i < 4; ++i)                              \
        _Pragma("unroll") for (int j = 0; j < 4; ++j)                          \
            acc[i][j] = f4{0.f, 0.f, 0.f, 0.f};                                \
    int aswz = lm & 7;                                                         \
    for (int kt = 0; kt < 8; ++kt) {                                           \
        __syncthreads();                                                       \
        _Pragma("unroll") for (int i = 0; i < 4; ++i) {                        \
            gl_lds16(Ag + kt * 64 + i * 8 * 512, Al + i * 8 * 64);             \
            gl_lds16(Bg + kt * 64 + i * 8 * 512, Bl + i * 8 * 64);             \
        }                                                                      \
        __syncthreads();                                                       \
        _Pragma("unroll") for (int s = 0; s < 2; ++s) {                        \
            short8 aF[4], bF[4];                                               \
            int slot = ((s * 4 + quad) ^ aswz) << 3;                           \
            _Pragma("unroll") for (int mt = 0; mt < 4; ++mt)                   \
                aF[mt] = *(const short8*)(As + (wy * 64 + mt * 16 + lm) * 64 + slot); \
            _Pragma("unroll") for (int nt = 0; nt < 4; ++nt)                   \
                bF[nt] = *(const short8*)(Bs + (wx * 64 + nt * 16 + lm) * 64 + slot); \
            _Pragma("unroll") for (int mt = 0; mt < 4; ++mt)                   \
                _Pragma("unroll") for (int nt = 0; nt < 4; ++nt)               \
                    acc[mt][nt] = MFMA16(aF[mt], bF[nt], acc[mt][nt]);         \
        }                                                                      \
    }

// ======================= prep: transposes + casts + zero-init ==============
__global__ void prep_k(const float* __restrict__ z, const float* __restrict__ cbk,
                       const float* __restrict__ Wq, const float* __restrict__ Wv,
                       float* __restrict__ X, __hip_bfloat16* __restrict__ Xh,
                       __hip_bfloat16* __restrict__ cbh,
                       __hip_bfloat16* __restrict__ WqT, __hip_bfloat16* __restrict__ WvT,
                       u64* __restrict__ packed, unsigned int* __restrict__ Kmax2i) {
    __shared__ float smem[33 * 32];
    int bx = blockIdx.x;
    if (bx < 2048) {
        float (*tile)[33] = (float(*)[33])smem;
        int t0 = (bx & 31) * 32, c0 = ((bx >> 5) & 15) * 32, b = bx >> 9;
        int tx = threadIdx.x & 31, ty = threadIdx.x >> 5;
        #pragma unroll
        for (int i = 0; i < 4; ++i) {
            int c = ty + i * 8;
            tile[c][tx] = z[((b << 9) + c0 + c) * 1024 + t0 + tx];
        }
        __syncthreads();
        #pragma unroll
        for (int i = 0; i < 4; ++i) {
            int tl = ty + i * 8;
            int tok = (b << 10) + t0 + tl;
            Xh[tok * 512 + c0 + tx] = __float2bfloat16(tile[tx][tl]);
        }
        float m = 0.25f * (tile[tx][ty * 4] + tile[tx][ty * 4 + 1] +
                           tile[tx][ty * 4 + 2] + tile[tx][ty * 4 + 3]);
        int tq = (t0 >> 2) + ty;
        X[(NFULL + (b << 8) + tq) * 512 + c0 + tx] = m;
    } else if (bx < 4096) {
        int i0 = (bx - 2048) * 1024 + threadIdx.x * 4;
        float4 v = *(const float4*)(cbk + i0);
        __hip_bfloat16* d = cbh + i0;
        d[0] = __float2bfloat16(v.x); d[1] = __float2bfloat16(v.y);
        d[2] = __float2bfloat16(v.z); d[3] = __float2bfloat16(v.w);
    } else if (bx < 4608) {
        int lin = bx - 4096;
        const float* W = (lin >> 8) ? Wv : Wq;
        __hip_bfloat16* WT = (lin >> 8) ? WvT : WqT;
        float (*t)[33] = (float(*)[33])smem;
        int bk = ((lin >> 4) & 15) * 32, bn = (lin & 15) * 32;
        int lx = threadIdx.x & 31, ly = threadIdx.x >> 5;
        #pragma unroll
        for (int i = 0; i < 4; ++i) {
            int r = ly * 4 + i;
            t[r][lx] = W[(bk + r) * 512 + bn + lx];
        }
        __syncthreads();
        #pragma unroll
        for (int i = 0; i < 4; ++i) {
            int r = ly * 4 + i;
            WT[(bn + r) * 512 + bk + lx] = __float2bfloat16(t[lx][r]);
        }
    } else {
        int i = (bx - 4608) * 256 + threadIdx.x;     // 0..4095
        packed[i] = 0ull;
        if (bx == 4608 && threadIdx.x == 0) Kmax2i[0] = 0u;
    }
}

// ======================= mid1: fp32 proj | pool-c (both depend on prep) ====
__global__ __launch_bounds__(256) void mid1_k(
    const __hip_bfloat16* __restrict__ Xh,
    const float* __restrict__ cbk, const float* __restrict__ Xp,
    const float* __restrict__ Wk, const float* __restrict__ Wq,
    const float* __restrict__ Wp, const float* __restrict__ bp,
    float* __restrict__ P0, float* __restrict__ P1, float* __restrict__ Cp) {
    __shared__ __align__(16) char smraw[16640];
    int bx = blockIdx.x, tid = threadIdx.x;
    if (bx < 640) {
        // ---------------- fp32 split-K projection ---------------------------
        float (*As2)[68]  = (float(*)[68])smraw;
        float (*Bs2)[132] = (float(*)[132])(smraw + 16 * 68 * 4);
        int kz = bx >= 320;
        int rem = bx - kz * 320;
        int mB = (rem % 80) * 64, nB = (rem / 80) * 128, kOff = kz * 256;
        const float *A, *B;
        if (mB < NFULL) { A = cbk + mB * 512; B = Wk; }
        else            { A = Xp + (mB - NFULL) * 512; B = Wq; }
        int ty = tid >> 4, tx = tid & 15;
        int arow = tid >> 2, achk = tid & 3;
        int brow = tid >> 4, bcol = (tid & 15) * 4;
        const float* Ap = A + arow * 512 + kOff + achk * 4;
        const float* Bp = B + (kOff + brow) * 512 + nB + bcol;
        float acc[4][8] = {};
        for (int kt = 0; kt < 16; ++kt) {
            float4 a  = *(const float4*)(Ap + kt * 16);
            float4 b0 = *(const float4*)(Bp + kt * 16 * 512);
            float4 b1 = *(const float4*)(Bp + kt * 16 * 512 + 64);
            __syncthreads();
            As2[achk * 4 + 0][arow] = a.x; As2[achk * 4 + 1][arow] = a.y;
            As2[achk * 4 + 2][arow] = a.z; As2[achk * 4 + 3][arow] = a.w;
            *(float4*)&Bs2[brow][bcol]      = b0;
            *(float4*)&Bs2[brow][bcol + 64] = b1;
            __syncthreads();
            #pragma unroll
            for (int kk = 0; kk < 16; ++kk) {
                float4 av  = *(const float4*)&As2[kk][ty * 4];
                float4 bv0 = *(const float4*)&Bs2[kk][tx * 4];
                float4 bv1 = *(const float4*)&Bs2[kk][64 + tx * 4];
                float a4[4] = {av.x, av.y, av.z, av.w};
                float b8[8] = {bv0.x, bv0.y, bv0.z, bv0.w, bv1.x, bv1.y, bv1.z, bv1.w};
                #pragma unroll
                for (int i = 0; i < 4; ++i)
                    #pragma unroll
                    for (int j = 0; j < 8; ++j)
                        acc[i][j] = fmaf(a4[i], b8[j], acc[i][j]);
            }
        }
        float* P = kz ? P1 : P0;
        #pragma unroll
        for (int i = 0; i < 4; ++i) {
            int row = mB + ty * 4 + i;
            float4 r0, r1;
            r0.x = acc[i][0]; r0.y = acc[i][1]; r0.z = acc[i][2]; r0.w = acc[i][3];
            r1.x = acc[i][4]; r1.y = acc[i][5]; r1.z = acc[i][6]; r1.w = acc[i][7];
            *(float4*)&P[row * 512 + nB + tx * 4]      = r0;
            *(float4*)&P[row * 512 + nB + 64 + tx * 4] = r1;
        }
    } else {
        // ---------------- head-pool weights Cp ------------------------------
        float* Wl = (float*)smraw;             // 4160 floats: lane stride 65
        for (int i = tid; i < 4096; i += 256) Wl[i + (i >> 6)] = Wp[i];
        __syncthreads();
        int w = tid >> 6, lane = tid & 63;
        int tok = (bx - 640) * 4 + w;          // 0..5119
        float x[8];
        if (tok < NFULL) {
            short8 xv = *(const short8*)(Xh + tok * 512 + lane * 8);
            #pragma unroll
            for (int j = 0; j < 8; ++j)
                x[j] = __uint_as_float(((unsigned)(unsigned short)xv[j]) << 16);
        } else {
            const float* xp = Xp + (tok - NFULL) * 512 + lane * 8;
            float4 a = *(const float4*)xp, b = *(const float4*)(xp + 4);
            x[0] = a.x; x[1] = a.y; x[2] = a.z; x[3] = a.w;
            x[4] = b.x; x[5] = b.y; x[6] = b.z; x[7] = b.w;
        }
        float s[8] = {};
        int base = lane * 65;
        #pragma unroll
        for (int j = 0; j < 8; ++j)
            #pragma unroll
            for (int h = 0; h < 8; ++h)
                s[h] = fmaf(x[j], Wl[base + j * 8 + h], s[h]);
        #pragma unroll
        for (int h = 0; h < 8; ++h)
            #pragma unroll
            for (int o = 32; o > 0; o >>= 1) s[h] += __shfl_xor(s[h], o);
        if (lane == 0) {
            #pragma unroll
            for (int h = 0; h < 8; ++h) Cp[tok * 8 + h] = s[h] + bp[h];
        }
    }
}

// ======================= mid2: bf16 bgemms | split-K norm-finish ===========
// [0,256): MFMA GEMMs (Qproj+norm reads Cp - ordered after mid1; Vproj).
// [256,1536): norm-finish, WAVE-PER-ROW, 4 rows/block.
// NOTE: smraw MUST be 32768 B — BGEMM3_CORE uses As (16 KB) + Bs (16 KB).
__global__ __launch_bounds__(256) void mid2_k(
    const __hip_bfloat16* __restrict__ Xh, const __hip_bfloat16* __restrict__ WqT,
    const __hip_bfloat16* __restrict__ cbh, const __hip_bfloat16* __restrict__ WvT,
    const float* __restrict__ P0, const float* __restrict__ P1,
    const float* __restrict__ bk, const float* __restrict__ bq,
    const float* __restrict__ gk, const float* __restrict__ gq,
    const float* __restrict__ Cp, const float* __restrict__ bvv,
    __hip_bfloat16* __restrict__ Qh, float* __restrict__ Vb,
    float* __restrict__ Kn, __hip_bfloat16* __restrict__ Kh,
    float* __restrict__ Qpool, unsigned int* __restrict__ Kmax2i) {
    __shared__ __align__(16) char smraw[32768];
    int bx = blockIdx.x, tid = threadIdx.x;
    if (bx < 256) {
        int part = bx >> 7, rem = bx & 127;
        int mB = (rem & 31) * 128, nB = (rem >> 5) * 128;
        const __hip_bfloat16* AM = part ? cbh : Xh;
        const __hip_bfloat16* Bt = part ? WvT : WqT;
        __hip_bfloat16* As = (__hip_bfloat16*)smraw;
        __hip_bfloat16* Bs = As + 128 * 64;
        BGEMM3_CORE(AM, Bt)
        if (part == 0) {
            int h = (rem >> 5) * 2 + wx;
            float bb[4], gg[4];
            #pragma unroll
            for (int nt = 0; nt < 4; ++nt) {
                bb[nt] = bq[h * 64 + nt * 16 + lm];
                gg[nt] = gq[nt * 16 + lm];
            }
            #pragma unroll
            for (int mt = 0; mt < 4; ++mt)
                #pragma unroll
                for (int reg = 0; reg < 4; ++reg) {
                    int tok = mB + wy * 64 + mt * 16 + quad * 4 + reg;
                    float vv[4], ss = 0.f;
                    #pragma unroll
                    for (int nt = 0; nt < 4; ++nt) {
                        vv[nt] = acc[mt][nt][reg] + bb[nt];
                        ss = fmaf(vv[nt], vv[nt], ss);
                    }
                    #pragma unroll
                    for (int off = 1; off < 16; off <<= 1) ss += __shfl_xor(ss, off);
                    float sc = rsqrtf(ss * (1.0f / 64.0f) + 1e-5f) *
                               Cp[tok * 8 + h] * 0.04419417382415922f;  // 1/(8*sqrt8)
                    #pragma unroll
                    for (int nt = 0; nt < 4; ++nt)
                        Qh[tok * 512 + h * 64 + nt * 16 + lm] =
                            __float2bfloat16(vv[nt] * sc * gg[nt]);
                }
        } else {
            float bb[4];
            #pragma unroll
            for (int nt = 0; nt < 4; ++nt) bb[nt] = bvv[nB + wx * 64 + nt * 16 + lm];
            #pragma unroll
            for (int mt = 0; mt < 4; ++mt)
                #pragma unroll
                for (int reg = 0; reg < 4; ++reg) {
                    int m = mB + wy * 64 + mt * 16 + quad * 4 + reg;
                    #pragma unroll
                    for (int nt = 0; nt < 4; ++nt)
                        Vb[m * 512 + nB + wx * 64 + nt * 16 + lm] =
                            acc[mt][nt][reg] + bb[nt];
                }
        }
    } else {
        // ---------------- split-K reduce + rmsnorm (wave-per-row) -----------
        int w = tid >> 6, lane = tid & 63;
        int row = (bx - 256) * 4 + w;      // 0..5119
        bool isQ = row >= NFULL;
        const float* bias = isQ ? bq : bk;
        const float* g = isQ ? gq : gk;
        int c0 = lane * 8;                 // 8 contiguous cols per lane
        const float* p0 = P0 + row * 512 + c0;
        const float* p1 = P1 + row * 512 + c0;
        float4 a0 = *(const float4*)p0,  a1 = *(const float4*)(p0 + 4);
        float4 d0 = *(const float4*)p1,  d1 = *(const float4*)(p1 + 4);
        float4 e0 = *(const float4*)(bias + c0), e1 = *(const float4*)(bias + c0 + 4);
        int gi = (lane & 7) * 8;
        float4 g0 = *(const float4*)(g + gi), g1 = *(const float4*)(g + gi + 4);
        float v[8];
        v[0] = a0.x + d0.x + e0.x; v[1] = a0.y + d0.y + e0.y;
        v[2] = a0.z + d0.z + e0.z; v[3] = a0.w + d0.w + e0.w;
        v[4] = a1.x + d1.x + e1.x; v[5] = a1.y + d1.y + e1.y;
        v[6] = a1.z + d1.z + e1.z; v[7] = a1.w + d1.w + e1.w;
        // per-head (64-col) sum-of-squares: 8 lanes per head
        float ss = 0.f;
        #pragma unroll
        for (int j = 0; j < 8; ++j) ss = fmaf(v[j], v[j], ss);
        ss += __shfl_xor(ss, 1); ss += __shfl_xor(ss, 2); ss += __shfl_xor(ss, 4);
        float sc = rsqrtf(ss * (1.0f / 64.0f) + 1e-5f);
        float gg[8] = {g0.x, g0.y, g0.z, g0.w, g1.x, g1.y, g1.z, g1.w};
        float o_[8];
        #pragma unroll
        for (int j = 0; j < 8; ++j) o_[j] = v[j] * sc * gg[j];
        if (isQ) {
            float cf = Cp[row * 8 + (lane >> 3)] * 0.04419417382415922f;
            #pragma unroll
            for (int j = 0; j < 8; ++j) o_[j] *= cf;
            float* qp = Qpool + (row - NFULL) * 512 + c0;
            *(float4*)qp       = make_float4(o_[0], o_[1], o_[2], o_[3]);
            *(float4*)(qp + 4) = make_float4(o_[4], o_[5], o_[6], o_[7]);
            __hip_bfloat16 hb[8];
            #pragma unroll
            for (int j = 0; j < 8; ++j) hb[j] = __float2bfloat16(o_[j]);
            *(short8*)(Qh + row * 512 + c0) = *(const short8*)hb;
        } else {
            float* kp = Kn + row * 512 + c0;
            *(float4*)kp       = make_float4(o_[0], o_[1], o_[2], o_[3]);
            *(float4*)(kp + 4) = make_float4(o_[4], o_[5], o_[6], o_[7]);
            __hip_bfloat16 hb[8];
            #pragma unroll
            for (int j = 0; j < 8; ++j) hb[j] = __float2bfloat16(o_[j]);
            *(short8*)(Kh + row * 512 + c0) = *(const short8*)hb;
            float rs = 0.f;
            #pragma unroll
            for (int j = 0; j < 8; ++j) rs = fmaf(o_[j], o_[j], rs);
            #pragma unroll
            for (int o = 32; o > 0; o >>= 1) rs += __shfl_xor(rs, o);
            float* wsum = (float*)smraw;
            if (lane == 0) wsum[w] = rs;
            __syncthreads();
            if (tid == 0) {
                float m01 = fmaxf(wsum[0], wsum[1]);
                float m23 = fmaxf(wsum[2], wsum[3]);
                atomicMax(Kmax2i, __float_as_uint(fmaxf(m01, m23)));
            }
        }
    }
}

// ==== logits over all 5120 tokens ==========================================
// r15: r14's counted-vmcnt schedule + XCD m-band locality swizzle.
// r14 proved the wall is SUPPLY, not drains: 327 MB / 55us = 5.9 TB/s with
// FETCH=19MB => all re-reads served by L3 (per-XCD working set ~5 MB > 4 MB
// L2 under default scatter => L2 thrash).  m97 sustains 13.4 TB/s staging
// on this chip when re-reads hit L2 -- the gap is L2 hit rate only.
// Swizzle: XCD j owns m-band [5j,5j+5), m fastest: per-XCD set = 5 Qh
// panels (640 KB, persistent) + sliding Kh window => L3 traffic 327->~37MB.
// (r11 tested this swizzle in a DRAIN-bound regime -> null; retest in the
// supply-bound regime it needs.  Correctness-neutral index remap.)
__global__ __launch_bounds__(256) void logits_full_k(
    const __hip_bfloat16* __restrict__ Qh, const __hip_bfloat16* __restrict__ Kh,
    u64* __restrict__ packed, __hip_bfloat16* __restrict__ Lp) {
    __shared__ __hip_bfloat16 As0[128 * 64];
    __shared__ __hip_bfloat16 Bs0[128 * 64];
    __shared__ __hip_bfloat16 As1[128 * 64];
    __shared__ __hip_bfloat16 Bs1[128 * 64];
    int tid = threadIdx.x;
    int id = blockIdx.x;                 // 0..1279
    int xcd = id & 7, local = id >> 3;   // 160 blocks per XCD
    int mIdx = xcd * 5 + (local % 5);    // 0..39 (5-panel m-band per XCD)
    int nIdx = local / 5;                // 0..31
    int mB = mIdx * 128, nB = nIdx * 128;
    int lane = tid & 63, w = tid >> 6, wy = w >> 1, wx = w & 1;
    int lm = lane & 15, quad = lane >> 4;
    int lr8 = lane >> 3;
    int kcs = (lane & 7) ^ lr8;
    int rS = w * 32 + lr8;
    const __hip_bfloat16* Ag = Qh + (mB + rS) * 512 + kcs * 8;
    const __hip_bfloat16* Bg = Kh + (nB + rS) * 512 + kcs * 8;
    int ldso = (w * 32) * 64 + lane * 8;
    f4 acc[4][4];
    #pragma unroll
    for (int i = 0; i < 4; ++i)
        #pragma unroll
        for (int j = 0; j < 4; ++j) acc[i][j] = f4{0.f, 0.f, 0.f, 0.f};
    int aswz = lm & 7;
    // prologue: stage kt=0 into buf0 (8 loads in flight)
    #pragma unroll
    for (int i = 0; i < 4; ++i) {
        gl_lds16(Ag + i * 8 * 512, As0 + ldso + i * 8 * 64);
        gl_lds16(Bg + i * 8 * 512, Bs0 + ldso + i * 8 * 64);
    }
    for (int kt = 0; kt < 8; ++kt) {
        __hip_bfloat16* Ac = (kt & 1) ? As1 : As0;
        __hip_bfloat16* Bc = (kt & 1) ? Bs1 : Bs0;
        // barrier1: all waves finished READING the buffer we are about to
        // overwrite (it was computed at kt-1, before each wave got here).
        __builtin_amdgcn_s_barrier();
        if (kt < 7) {
            __hip_bfloat16* An = (kt & 1) ? As0 : As1;
            __hip_bfloat16* Bn = (kt & 1) ? Bs0 : Bs1;
            #pragma unroll
            for (int i = 0; i < 4; ++i) {
                gl_lds16(Ag + (kt + 1) * 64 + i * 8 * 512, An + ldso + i * 8 * 64);
                gl_lds16(Bg + (kt + 1) * 64 + i * 8 * 512, Bn + ldso + i * 8 * 64);
            }
            // wait for THIS wave's current-buf loads (8 newest stay in flight)
            asm volatile("s_waitcnt vmcnt(8)" ::: "memory");
        } else {
            asm volatile("s_waitcnt vmcnt(0)" ::: "memory");
        }
        // barrier2: every wave's current-buf loads have landed.
        __builtin_amdgcn_s_barrier();
        __builtin_amdgcn_sched_barrier(0);
        #pragma unroll
        for (int s = 0; s < 2; ++s) {
            short8 aF[4], bF[4];
            int slot = ((s * 4 + quad) ^ aswz) << 3;
            #pragma unroll
            for (int mt = 0; mt < 4; ++mt)
                aF[mt] = *(const short8*)(Ac + (wy * 64 + mt * 16 + lm) * 64 + slot);
            #pragma unroll
            for (int nt = 0; nt < 4; ++nt)
                bF[nt] = *(const short8*)(Bc + (wx * 64 + nt * 16 + lm) * 64 + slot);
            #pragma unroll
            for (int mt = 0; mt < 4; ++mt)
                #pragma unroll
                for (int nt = 0; nt < 4; ++nt)
                    acc[mt][nt] = MFMA16(aF[mt], bF[nt], acc[mt][nt]);
        }
    }
    if (mIdx < 32) {
        // full-token rows: packed atomic argmax
        #pragma unroll
        for (int mt = 0; mt < 4; ++mt)
            #pragma unroll
            for (int reg = 0; reg < 4; ++reg) {
                float bv = -FLT_MAX; int bi = 0;
                #pragma unroll
                for (int nt = 0; nt < 4; ++nt) {
                    float v = acc[mt][nt][reg];
                    int n = nB + wx * 64 + nt * 16 + lm;
                    if (v > bv) { bv = v; bi = n; }
                }
                #pragma unroll
                for (int off = 1; off < 16; off <<= 1) {
                    float ov = __shfl_xor(bv, off);
                    int oi = __shfl_xor(bi, off);
                    if (ov > bv || (ov == bv && oi < bi)) { bv = ov; bi = oi; }
                }
                if (lm == 0) {
                    unsigned ub = __float_as_uint(bv);
                    ub = (ub & 0x80000000u) ? ~ub : (ub | 0x80000000u);
                    u64 key = ((u64)ub << 32) | (u64)(0xFFFFFFFFu - (unsigned)bi);
                    int tok = mB + wy * 64 + mt * 16 + quad * 4 + reg;
                    atomicMax(&packed[tok], key);
                }
            }
    } else {
        // pooled rows: bf16 logit rows for candidate rescore
        #pragma unroll
        for (int mt = 0; mt < 4; ++mt)
            #pragma unroll
            for (int reg = 0; reg < 4; ++reg) {
                int tok = mB + wy * 64 + mt * 16 + quad * 4 + reg;
                long long base = (long long)(tok - NFULL) * 4096;
                #pragma unroll
                for (int nt = 0; nt < 4; ++nt)
                    Lp[base + nB + wx * 64 + nt * 16 + lm] =
                        __float2bfloat16(acc[mt][nt][reg]);
            }
    }
}

// ======================= tail: rescore | hist+perplexity ===================
__global__ __launch_bounds__(256) void tail_k(
    const float* __restrict__ Qpool, const float* __restrict__ Kn,
    const __hip_bfloat16* __restrict__ Lp, const unsigned int* __restrict__ Kmax2i,
    const u64* __restrict__ packed, int* __restrict__ codeP,
    float* __restrict__ outPpl) {
    __shared__ int cnt[4096];
    __shared__ float red[4];
    int tid = threadIdx.x;
    if (blockIdx.x < 256) {
        int wid = tid >> 6, lane = tid & 63;
        int tok = blockIdx.x * 4 + wid;
        const float* q = Qpool + tok * 512;
        float4 q0 = *(const float4*)(q + lane * 8);
        float4 q1 = *(const float4*)(q + lane * 8 + 4);
        float qs = q0.x * q0.x + q0.y * q0.y + q0.z * q0.z + q0.w * q0.w +
                   q1.x * q1.x + q1.y * q1.y + q1.z * q1.z + q1.w * q1.w;
        #pragma unroll
        for (int o = 32; o > 0; o >>= 1) qs += __shfl_xor(qs, o);
        float delta = 0.0078125f * sqrtf(qs) * sqrtf(__uint_as_float(*Kmax2i));
        const __hip_bfloat16* row = Lp + (long long)tok * 4096;
        float mx = -FLT_MAX;
        for (int c = 0; c < 64; ++c)
            mx = fmaxf(mx, __bfloat162float(row[c * 64 + lane]));
        #pragma unroll
        for (int o = 32; o > 0; o >>= 1) mx = fmaxf(mx, __shfl_xor(mx, o));
        float thr = mx - delta;
        float bv = -FLT_MAX; int bi = 0;
        for (int c = 0; c < 64; ++c) {
            float v = __bfloat162float(row[c * 64 + lane]);
            u64 mask = __ballot(v >= thr);
            while (mask) {
                int l = __ffsll((long long)mask) - 1;
                mask &= mask - 1;
                int n = c * 64 + l;
                const float* k = Kn + n * 512;
                float4 k0 = *(const float4*)(k + lane * 8);
                float4 k1 = *(const float4*)(k + lane * 8 + 4);
                float d = q0.x * k0.x;
                d = fmaf(q0.y, k0.y, d); d = fmaf(q0.z, k0.z, d); d = fmaf(q0.w, k0.w, d);
                d = fmaf(q1.x, k1.x, d); d = fmaf(q1.y, k1.y, d);
                d = fmaf(q1.z, k1.z, d); d = fmaf(q1.w, k1.w, d);
                #pragma unroll
                for (int o = 32; o > 0; o >>= 1) d += __shfl_xor(d, o);
                if (d > bv) { bv = d; bi = n; }   // ascending n => first-max wins
            }
        }
        if (lane == 0) codeP[tok] = bi;
    } else {
        for (int i = tid; i < 4096; i += 256) cnt[i] = 0;
        __syncthreads();
        for (int i = tid; i < 4096; i += 256) {
            int bi = (int)(0xFFFFFFFFu - (unsigned)(packed[i] & 0xFFFFFFFFu));
            atomicAdd(&cnt[bi], 1);
        }
        __syncthreads();
        float s = 0.f;
        for (int i = tid; i < 4096; i += 256) {
            float p = (float)cnt[i] * (1.0f / 4096.0f);
            s += p * logf(p + 1e-7f);
        }
        #pragma unroll
        for (int o = 32; o > 0; o >>= 1) s += __shfl_xor(s, o);
        if ((tid & 63) == 0) red[tid >> 6] = s;
        __syncthreads();
        if (tid == 0)
            outPpl[0] = expf(-(red[0] + red[1] + red[2] + red[3]));
    }
}

// ======================= z_hat: wave per (b, j) ============================
__global__ void zhat_k(const float* __restrict__ Vv, const int* __restrict__ codeP,
                       float* __restrict__ out) {
    int w = (blockIdx.x << 2) + (threadIdx.x >> 6);   // 0..1023
    int lane = threadIdx.x & 63;
    int b = w >> 8, j = w & 255;
    const int* cb = codeP + (b << 8);
    const float* rm = Vv + cb[max(j - 1, 0)] * 512;
    const float* r0 = Vv + cb[j] * 512;
    const float* rp = Vv + cb[min(j + 1, 255)] * 512;
    #pragma unroll
    for (int i = 0; i < 8; ++i) {
        int c = i * 64 + lane;
        float vm = rm[c], v0 = r0[c], vp = rp[c];
        float4 o;
        o.x = 0.375f * vm + 0.625f * v0;
        o.y = 0.125f * vm + 0.875f * v0;
        o.z = 0.875f * v0 + 0.125f * vp;
        o.w = 0.625f * v0 + 0.375f * vp;
        *(float4*)&out[(((b << 9) + c) << 10) + (j << 2)] = o;
    }
}

extern "C" void kernel_launch(void* const* d_in, const int* in_sizes, int n_in,
                              void* d_out, int out_size, void* d_ws, size_t ws_size,
                              hipStream_t stream) {
    const float* z   = (const float*)d_in[0];
    const float* cbk = (const float*)d_in[2];
    const float* Wq  = (const float*)d_in[3];
    const float* bq  = (const float*)d_in[4];
    const float* Wk  = (const float*)d_in[5];
    const float* bk  = (const float*)d_in[6];
    const float* Wv  = (const float*)d_in[7];
    const float* bv  = (const float*)d_in[8];
    const float* Wp  = (const float*)d_in[9];
    const float* bp  = (const float*)d_in[10];
    const float* gq  = (const float*)d_in[11];
    const float* gk  = (const float*)d_in[12];
    float* out = (float*)d_out;

    // ---- workspace layout ----
    float* X      = (float*)d_ws;            // 5120*512 (only pooled rows used)
    float* Qpool  = X + 5120 * 512;          // 1024*512
    float* Kn     = Qpool + 1024 * 512;      // 4096*512
    float* Vb     = Kn + 4096 * 512;         // 4096*512
    float* Cp     = Vb + 4096 * 512;         // 5120*8
    float* P0     = Cp + 5120 * 8;           // 5120*512 (aliased by Lp later)
    float* P1     = P0 + 5120 * 512;         // 5120*512
    u64*   packed = (u64*)(P1 + 5120 * 512); // 4096
    unsigned int* Kmax2i = (unsigned int*)(packed + 4096);  // 4
    int*   codeP  = (int*)(Kmax2i + 4);      // 1024
    __hip_bfloat16* Qh  = (__hip_bfloat16*)(codeP + 1024);  // 5120*512
    __hip_bfloat16* Kh  = Qh + 5120 * 512;   // 4096*512
    __hip_bfloat16* Xh  = Kh + 4096 * 512;   // 4096*512
    __hip_bfloat16* cbh = Xh + 4096 * 512;   // 4096*512
    __hip_bfloat16* WqT = cbh + 4096 * 512;  // 512*512
    __hip_bfloat16* WvT = WqT + 512 * 512;   // 512*512
    __hip_bfloat16* Lp  = (__hip_bfloat16*)P0;  // alias: 1024*4096 bf16

    prep_k<<<4624, 256, 0, stream>>>(z, cbk, Wq, Wv, X, Xh, cbh, WqT, WvT,
                                     packed, Kmax2i);
    mid1_k<<<1920, 256, 0, stream>>>(Xh, cbk, X + 4096 * 512, Wk, Wq, Wp, bp,
                                     P0, P1, Cp);
    mid2_k<<<1536, 256, 0, stream>>>(Xh, WqT, cbh, WvT, P0, P1, bk, bq, gk, gq,
                                     Cp, bv, Qh, Vb, Kn, Kh, Qpool, Kmax2i);
    logits_full_k<<<1280, 256, 0, stream>>>(Qh, Kh, packed, Lp);
    tail_k<<<257, 256, 0, stream>>>(Qpool, Kn, Lp, Kmax2i, packed, codeP,
                                    out + 4 * 512 * 1024);
    zhat_k<<<256, 256, 0, stream>>>(Vb, codeP, out);
}

// Round 7
// 223.672 us; speedup vs baseline: 1.1148x; 1.0276x over previous
//
#include <hip/hip_runtime.h>
#include <hip/hip_bf16.h>
#include <cfloat>
#include <math.h>

#define NFULL 4096
#define NPOOL 1024
#define NTOK  5120
#define VDIM  4096

typedef __attribute__((ext_vector_type(8))) short short8;   // 8 bf16 (4 VGPR)
typedef __attribute__((ext_vector_type(4))) float f4;       // MFMA acc
typedef unsigned long long u64;

#define MFMA16(a,b,c) __builtin_amdgcn_mfma_f32_16x16x32_bf16((a),(b),(c),0,0,0)

static __device__ __forceinline__ void gl_lds16(const void* g, void* l) {
    __builtin_amdgcn_global_load_lds(
        (const __attribute__((address_space(1))) unsigned int*)g,
        (__attribute__((address_space(3))) unsigned int*)l, 16, 0, 0);
}

// ==== bf16 MFMA 128x128 core, BK=64, XOR-swizzled LDS (r4-verified) ========
// Requires As, Bs to span 128*64 bf16 (16 KB) EACH.  Single-buffered,
// 2 barriers per K-step.  Used by mid2_k (proven; limits blast radius).
#define BGEMM3_CORE(AM, Bt)                                                    \
    int lane = tid & 63, w = tid >> 6, wy = w >> 1, wx = w & 1;                \
    int lm = lane & 15, quad = lane >> 4;                                      \
    int lr8 = lane >> 3;                                                       \
    int kcs = (lane & 7) ^ lr8;                                                \
    int rS = w * 32 + lr8;                                                     \
    const __hip_bfloat16* Ag = (AM) + (mB + rS) * 512 + kcs * 8;               \
    const __hip_bfloat16* Bg = (Bt) + (nB + rS) * 512 + kcs * 8;               \
    __hip_bfloat16* Al = As + (w * 32) * 64 + lane * 8;                        \
    __hip_bfloat16* Bl = Bs + (w * 32) * 64 + lane * 8;                        \
    f4 acc[4][4];                                                              \
    _Pragma("unroll") for (int i = 0; i < 4; ++i)                              \
        _Pragma("unroll") for (int j = 0; j < 4; ++j)                          \
            acc[i][j] = f4{0.f, 0.f, 0.f, 0.f};                                \
    int aswz = lm & 7;                                                         \
    for (int kt = 0; kt < 8; ++kt) {                                           \
        __syncthreads();                                                       \
        _Pragma("unroll") for (int i = 0; i < 4; ++i) {                        \
            gl_lds16(Ag + kt * 64 + i * 8 * 512, Al + i * 8 * 64);             \
            gl_lds16(Bg + kt * 64 + i * 8 * 512, Bl + i * 8 * 64);             \
        }                                                                      \
        __syncthreads();                                                       \
        _Pragma("unroll") for (int s = 0; s < 2; ++s) {                        \
            short8 aF[4], bF[4];                                               \
            int slot = ((s * 4 + quad) ^ aswz) << 3;                           \
            _Pragma("unroll") for (int mt = 0; mt < 4; ++mt)                   \
                aF[mt] = *(const short8*)(As + (wy * 64 + mt * 16 + lm) * 64 + slot); \
            _Pragma("unroll") for (int nt = 0; nt < 4; ++nt)                   \
                bF[nt] = *(const short8*)(Bs + (wx * 64 + nt * 16 + lm) * 64 + slot); \
            _Pragma("unroll") for (int mt = 0; mt < 4; ++mt)                   \
                _Pragma("unroll") for (int nt = 0; nt < 4; ++nt)               \
                    acc[mt][nt] = MFMA16(aF[mt], bF[nt], acc[mt][nt]);         \
        }                                                                      \
    }

// ======================= prep: transposes + casts + zero-init ==============
__global__ void prep_k(const float* __restrict__ z, const float* __restrict__ cbk,
                       const float* __restrict__ Wq, const float* __restrict__ Wv,
                       float* __restrict__ X, __hip_bfloat16* __restrict__ Xh,
                       __hip_bfloat16* __restrict__ cbh,
                       __hip_bfloat16* __restrict__ WqT, __hip_bfloat16* __restrict__ WvT,
                       u64* __restrict__ packed, unsigned int* __restrict__ Kmax2i) {
    __shared__ float smem[33 * 32];
    int bx = blockIdx.x;
    if (bx < 2048) {
        float (*tile)[33] = (float(*)[33])smem;
        int t0 = (bx & 31) * 32, c0 = ((bx >> 5) & 15) * 32, b = bx >> 9;
        int tx = threadIdx.x & 31, ty = threadIdx.x >> 5;
        #pragma unroll
        for (int i = 0; i < 4; ++i) {
            int c = ty + i * 8;
            tile[c][tx] = z[((b << 9) + c0 + c) * 1024 + t0 + tx];
        }
        __syncthreads();
        #pragma unroll
        for (int i = 0; i < 4; ++i) {
            int tl = ty + i * 8;
            int tok = (b << 10) + t0 + tl;
            Xh[tok * 512 + c0 + tx] = __float2bfloat16(tile[tx][tl]);
        }
        float m = 0.25f * (tile[tx][ty * 4] + tile[tx][ty * 4 + 1] +
                           tile[tx][ty * 4 + 2] + tile[tx][ty * 4 + 3]);
        int tq = (t0 >> 2) + ty;
        X[(NFULL + (b << 8) + tq) * 512 + c0 + tx] = m;
    } else if (bx < 4096) {
        int i0 = (bx - 2048) * 1024 + threadIdx.x * 4;
        float4 v = *(const float4*)(cbk + i0);
        __hip_bfloat16* d = cbh + i0;
        d[0] = __float2bfloat16(v.x); d[1] = __float2bfloat16(v.y);
        d[2] = __float2bfloat16(v.z); d[3] = __float2bfloat16(v.w);
    } else if (bx < 4608) {
        int lin = bx - 4096;
        const float* W = (lin >> 8) ? Wv : Wq;
        __hip_bfloat16* WT = (lin >> 8) ? WvT : WqT;
        float (*t)[33] = (float(*)[33])smem;
        int bk = ((lin >> 4) & 15) * 32, bn = (lin & 15) * 32;
        int lx = threadIdx.x & 31, ly = threadIdx.x >> 5;
        #pragma unroll
        for (int i = 0; i < 4; ++i) {
            int r = ly * 4 + i;
            t[r][lx] = W[(bk + r) * 512 + bn + lx];
        }
        __syncthreads();
        #pragma unroll
        for (int i = 0; i < 4; ++i) {
            int r = ly * 4 + i;
            WT[(bn + r) * 512 + bk + lx] = __float2bfloat16(t[lx][r]);
        }
    } else {
        int i = (bx - 4608) * 256 + threadIdx.x;     // 0..4095
        packed[i] = 0ull;
        if (bx == 4608 && threadIdx.x == 0) Kmax2i[0] = 0u;
    }
}

// ======================= mid1: fp32 proj | pool-c (both depend on prep) ====
__global__ __launch_bounds__(256) void mid1_k(
    const __hip_bfloat16* __restrict__ Xh,
    const float* __restrict__ cbk, const float* __restrict__ Xp,
    const float* __restrict__ Wk, const float* __restrict__ Wq,
    const float* __restrict__ Wp, const float* __restrict__ bp,
    float* __restrict__ P0, float* __restrict__ P1, float* __restrict__ Cp) {
    __shared__ __align__(16) char smraw[16640];
    int bx = blockIdx.x, tid = threadIdx.x;
    if (bx < 640) {
        // ---------------- fp32 split-K projection ---------------------------
        float (*As2)[68]  = (float(*)[68])smraw;
        float (*Bs2)[132] = (float(*)[132])(smraw + 16 * 68 * 4);
        int kz = bx >= 320;
        int rem = bx - kz * 320;
        int mB = (rem % 80) * 64, nB = (rem / 80) * 128, kOff = kz * 256;
        const float *A, *B;
        if (mB < NFULL) { A = cbk + mB * 512; B = Wk; }
        else            { A = Xp + (mB - NFULL) * 512; B = Wq; }
        int ty = tid >> 4, tx = tid & 15;
        int arow = tid >> 2, achk = tid & 3;
        int brow = tid >> 4, bcol = (tid & 15) * 4;
        const float* Ap = A + arow * 512 + kOff + achk * 4;
        const float* Bp = B + (kOff + brow) * 512 + nB + bcol;
        float acc[4][8] = {};
        for (int kt = 0; kt < 16; ++kt) {
            float4 a  = *(const float4*)(Ap + kt * 16);
            float4 b0 = *(const float4*)(Bp + kt * 16 * 512);
            float4 b1 = *(const float4*)(Bp + kt * 16 * 512 + 64);
            __syncthreads();
            As2[achk * 4 + 0][arow] = a.x; As2[achk * 4 + 1][arow] = a.y;
            As2[achk * 4 + 2][arow] = a.z; As2[achk * 4 + 3][arow] = a.w;
            *(float4*)&Bs2[brow][bcol]      = b0;
            *(float4*)&Bs2[brow][bcol + 64] = b1;
            __syncthreads();
            #pragma unroll
            for (int kk = 0; kk < 16; ++kk) {
                float4 av  = *(const float4*)&As2[kk][ty * 4];
                float4 bv0 = *(const float4*)&Bs2[kk][tx * 4];
                float4 bv1 = *(const float4*)&Bs2[kk][64 + tx * 4];
                float a4[4] = {av.x, av.y, av.z, av.w};
                float b8[8] = {bv0.x, bv0.y, bv0.z, bv0.w, bv1.x, bv1.y, bv1.z, bv1.w};
                #pragma unroll
                for (int i = 0; i < 4; ++i)
                    #pragma unroll
                    for (int j = 0; j < 8; ++j)
                        acc[i][j] = fmaf(a4[i], b8[j], acc[i][j]);
            }
        }
        float* P = kz ? P1 : P0;
        #pragma unroll
        for (int i = 0; i < 4; ++i) {
            int row = mB + ty * 4 + i;
            float4 r0, r1;
            r0.x = acc[i][0]; r0.y = acc[i][1]; r0.z = acc[i][2]; r0.w = acc[i][3];
            r1.x = acc[i][4]; r1.y = acc[i][5]; r1.z = acc[i][6]; r1.w = acc[i][7];
            *(float4*)&P[row * 512 + nB + tx * 4]      = r0;
            *(float4*)&P[row * 512 + nB + 64 + tx * 4] = r1;
        }
    } else {
        // ---------------- head-pool weights Cp ------------------------------
        float* Wl = (float*)smraw;             // 4160 floats: lane stride 65
        for (int i = tid; i < 4096; i += 256) Wl[i + (i >> 6)] = Wp[i];
        __syncthreads();
        int w = tid >> 6, lane = tid & 63;
        int tok = (bx - 640) * 4 + w;          // 0..5119
        float x[8];
        if (tok < NFULL) {
            short8 xv = *(const short8*)(Xh + tok * 512 + lane * 8);
            #pragma unroll
            for (int j = 0; j < 8; ++j)
                x[j] = __uint_as_float(((unsigned)(unsigned short)xv[j]) << 16);
        } else {
            const float* xp = Xp + (tok - NFULL) * 512 + lane * 8;
            float4 a = *(const float4*)xp, b = *(const float4*)(xp + 4);
            x[0] = a.x; x[1] = a.y; x[2] = a.z; x[3] = a.w;
            x[4] = b.x; x[5] = b.y; x[6] = b.z; x[7] = b.w;
        }
        float s[8] = {};
        int base = lane * 65;
        #pragma unroll
        for (int j = 0; j < 8; ++j)
            #pragma unroll
            for (int h = 0; h < 8; ++h)
                s[h] = fmaf(x[j], Wl[base + j * 8 + h], s[h]);
        #pragma unroll
        for (int h = 0; h < 8; ++h)
            #pragma unroll
            for (int o = 32; o > 0; o >>= 1) s[h] += __shfl_xor(s[h], o);
        if (lane == 0) {
            #pragma unroll
            for (int h = 0; h < 8; ++h) Cp[tok * 8 + h] = s[h] + bp[h];
        }
    }
}

// ======================= mid2: bf16 bgemms | split-K norm-finish ===========
// [0,256): MFMA GEMMs (Qproj+norm reads Cp - ordered after mid1; Vproj).
// [256,1536): norm-finish, WAVE-PER-ROW, 4 rows/block.
// NOTE: smraw MUST be 32768 B — BGEMM3_CORE uses As (16 KB) + Bs (16 KB).
__global__ __launch_bounds__(256) void mid2_k(
    const __hip_bfloat16* __restrict__ Xh, const __hip_bfloat16* __restrict__ WqT,
    const __hip_bfloat16* __restrict__ cbh, const __hip_bfloat16* __restrict__ WvT,
    const float* __restrict__ P0, const float* __restrict__ P1,
    const float* __restrict__ bk, const float* __restrict__ bq,
    const float* __restrict__ gk, const float* __restrict__ gq,
    const float* __restrict__ Cp, const float* __restrict__ bvv,
    __hip_bfloat16* __restrict__ Qh, float* __restrict__ Vb,
    float* __restrict__ Kn, __hip_bfloat16* __restrict__ Kh,
    float* __restrict__ Qpool, unsigned int* __restrict__ Kmax2i) {
    __shared__ __align__(16) char smraw[32768];
    int bx = blockIdx.x, tid = threadIdx.x;
    if (bx < 256) {
        int part = bx >> 7, rem = bx & 127;
        int mB = (rem & 31) * 128, nB = (rem >> 5) * 128;
        const __hip_bfloat16* AM = part ? cbh : Xh;
        const __hip_bfloat16* Bt = part ? WvT : WqT;
        __hip_bfloat16* As = (__hip_bfloat16*)smraw;
        __hip_bfloat16* Bs = As + 128 * 64;
        BGEMM3_CORE(AM, Bt)
        if (part == 0) {
            int h = (rem >> 5) * 2 + wx;
            float bb[4], gg[4];
            #pragma unroll
            for (int nt = 0; nt < 4; ++nt) {
                bb[nt] = bq[h * 64 + nt * 16 + lm];
                gg[nt] = gq[nt * 16 + lm];
            }
            #pragma unroll
            for (int mt = 0; mt < 4; ++mt)
                #pragma unroll
                for (int reg = 0; reg < 4; ++reg) {
                    int tok = mB + wy * 64 + mt * 16 + quad * 4 + reg;
                    float vv[4], ss = 0.f;
                    #pragma unroll
                    for (int nt = 0; nt < 4; ++nt) {
                        vv[nt] = acc[mt][nt][reg] + bb[nt];
                        ss = fmaf(vv[nt], vv[nt], ss);
                    }
                    #pragma unroll
                    for (int off = 1; off < 16; off <<= 1) ss += __shfl_xor(ss, off);
                    float sc = rsqrtf(ss * (1.0f / 64.0f) + 1e-5f) *
                               Cp[tok * 8 + h] * 0.04419417382415922f;  // 1/(8*sqrt8)
                    #pragma unroll
                    for (int nt = 0; nt < 4; ++nt)
                        Qh[tok * 512 + h * 64 + nt * 16 + lm] =
                            __float2bfloat16(vv[nt] * sc * gg[nt]);
                }
        } else {
            float bb[4];
            #pragma unroll
            for (int nt = 0; nt < 4; ++nt) bb[nt] = bvv[nB + wx * 64 + nt * 16 + lm];
            #pragma unroll
            for (int mt = 0; mt < 4; ++mt)
                #pragma unroll
                for (int reg = 0; reg < 4; ++reg) {
                    int m = mB + wy * 64 + mt * 16 + quad * 4 + reg;
                    #pragma unroll
                    for (int nt = 0; nt < 4; ++nt)
                        Vb[m * 512 + nB + wx * 64 + nt * 16 + lm] =
                            acc[mt][nt][reg] + bb[nt];
                }
        }
    } else {
        // ---------------- split-K reduce + rmsnorm (wave-per-row) -----------
        int w = tid >> 6, lane = tid & 63;
        int row = (bx - 256) * 4 + w;      // 0..5119
        bool isQ = row >= NFULL;
        const float* bias = isQ ? bq : bk;
        const float* g = isQ ? gq : gk;
        int c0 = lane * 8;                 // 8 contiguous cols per lane
        const float* p0 = P0 + row * 512 + c0;
        const float* p1 = P1 + row * 512 + c0;
        float4 a0 = *(const float4*)p0,  a1 = *(const float4*)(p0 + 4);
        float4 d0 = *(const float4*)p1,  d1 = *(const float4*)(p1 + 4);
        float4 e0 = *(const float4*)(bias + c0), e1 = *(const float4*)(bias + c0 + 4);
        int gi = (lane & 7) * 8;
        float4 g0 = *(const float4*)(g + gi), g1 = *(const float4*)(g + gi + 4);
        float v[8];
        v[0] = a0.x + d0.x + e0.x; v[1] = a0.y + d0.y + e0.y;
        v[2] = a0.z + d0.z + e0.z; v[3] = a0.w + d0.w + e0.w;
        v[4] = a1.x + d1.x + e1.x; v[5] = a1.y + d1.y + e1.y;
        v[6] = a1.z + d1.z + e1.z; v[7] = a1.w + d1.w + e1.w;
        // per-head (64-col) sum-of-squares: 8 lanes per head
        float ss = 0.f;
        #pragma unroll
        for (int j = 0; j < 8; ++j) ss = fmaf(v[j], v[j], ss);
        ss += __shfl_xor(ss, 1); ss += __shfl_xor(ss, 2); ss += __shfl_xor(ss, 4);
        float sc = rsqrtf(ss * (1.0f / 64.0f) + 1e-5f);
        float gg[8] = {g0.x, g0.y, g0.z, g0.w, g1.x, g1.y, g1.z, g1.w};
        float o_[8];
        #pragma unroll
        for (int j = 0; j < 8; ++j) o_[j] = v[j] * sc * gg[j];
        if (isQ) {
            float cf = Cp[row * 8 + (lane >> 3)] * 0.04419417382415922f;
            #pragma unroll
            for (int j = 0; j < 8; ++j) o_[j] *= cf;
            float* qp = Qpool + (row - NFULL) * 512 + c0;
            *(float4*)qp       = make_float4(o_[0], o_[1], o_[2], o_[3]);
            *(float4*)(qp + 4) = make_float4(o_[4], o_[5], o_[6], o_[7]);
            __hip_bfloat16 hb[8];
            #pragma unroll
            for (int j = 0; j < 8; ++j) hb[j] = __float2bfloat16(o_[j]);
            *(short8*)(Qh + row * 512 + c0) = *(const short8*)hb;
        } else {
            float* kp = Kn + row * 512 + c0;
            *(float4*)kp       = make_float4(o_[0], o_[1], o_[2], o_[3]);
            *(float4*)(kp + 4) = make_float4(o_[4], o_[5], o_[6], o_[7]);
            __hip_bfloat16 hb[8];
            #pragma unroll
            for (int j = 0; j < 8; ++j) hb[j] = __float2bfloat16(o_[j]);
            *(short8*)(Kh + row * 512 + c0) = *(const short8*)hb;
            float rs = 0.f;
            #pragma unroll
            for (int j = 0; j < 8; ++j) rs = fmaf(o_[j], o_[j], rs);
            #pragma unroll
            for (int o = 32; o > 0; o >>= 1) rs += __shfl_xor(rs, o);
            float* wsum = (float*)smraw;
            if (lane == 0) wsum[w] = rs;
            __syncthreads();
            if (tid == 0) {
                float m01 = fmaxf(wsum[0], wsum[1]);
                float m23 = fmaxf(wsum[2], wsum[3]);
                atomicMax(Kmax2i, __float_as_uint(fmaxf(m01, m23)));
            }
        }
    }
}

// ==== logits over all 5120 tokens ==========================================
// r16: ASYMMETRIC 128x256 tile, BK=64, 512 threads (8 waves, 2m x 4n,
// per-wave 64x64 -> acc[4][4], same register footprint as the 54us db-128^2
// baseline).  Staged bytes/output scale as (BM+BN)/(BM*BN): 0.75x of 128^2
// (327 MB -> 245 MB) while LDS stays 48 KB single-buffered -> SAME
// 2-blocks/CU residency (r12's 256^2 cut bytes 2x but collapsed to
// 1 block/CU and lost it all).  Schedule = proven r0-style 2-barrier loop.
// Placement/pipelining levers are exhausted (swizzle null x2, counted
// vmcnt null, deep prefetch null) -- bytes x residency is the one untried
// combination.  __launch_bounds__(512,4): cap 128 VGPR, no spill.
__global__ __launch_bounds__(512, 4) void logits_full_k(
    const __hip_bfloat16* __restrict__ Qh, const __hip_bfloat16* __restrict__ Kh,
    u64* __restrict__ packed, __hip_bfloat16* __restrict__ Lp) {
    __shared__ __hip_bfloat16 As[128 * 64];   // 16 KB
    __shared__ __hip_bfloat16 Bs[256 * 64];   // 32 KB
    int tid = threadIdx.x;
    int mB = blockIdx.x * 128, nB = blockIdx.y * 256;   // grid (40, 16)
    int lane = tid & 63, w = tid >> 6;        // 8 waves
    int wy = w >> 2, wx = w & 3;              // wy: m-half (64), wx: n-quarter (64)
    int lm = lane & 15, quad = lane >> 4;
    int lr8 = lane >> 3;
    int kcs = (lane & 7) ^ lr8;               // XOR-swizzled source col-chunk
    const __hip_bfloat16* Ag = Qh + (mB + w * 16 + lr8) * 512 + kcs * 8;
    const __hip_bfloat16* Bg = Kh + (nB + w * 32 + lr8) * 512 + kcs * 8;
    __hip_bfloat16* Al = As + (w * 16) * 64 + lane * 8;
    __hip_bfloat16* Bl = Bs + (w * 32) * 64 + lane * 8;
    f4 acc[4][4];
    #pragma unroll
    for (int i = 0; i < 4; ++i)
        #pragma unroll
        for (int j = 0; j < 4; ++j) acc[i][j] = f4{0.f, 0.f, 0.f, 0.f};
    int aswz = lm & 7;
    for (int kt = 0; kt < 8; ++kt) {
        __syncthreads();
        #pragma unroll
        for (int i = 0; i < 2; ++i)           // A: 8 waves x 16 rows = 128
            gl_lds16(Ag + kt * 64 + i * 8 * 512, Al + i * 8 * 64);
        #pragma unroll
        for (int i = 0; i < 4; ++i)           // B: 8 waves x 32 rows = 256
            gl_lds16(Bg + kt * 64 + i * 8 * 512, Bl + i * 8 * 64);
        __syncthreads();
        #pragma unroll
        for (int s = 0; s < 2; ++s) {
            short8 aF[4], bF[4];
            int slot = ((s * 4 + quad) ^ aswz) << 3;
            #pragma unroll
            for (int mt = 0; mt < 4; ++mt)
                aF[mt] = *(const short8*)(As + (wy * 64 + mt * 16 + lm) * 64 + slot);
            #pragma unroll
            for (int nt = 0; nt < 4; ++nt)
                bF[nt] = *(const short8*)(Bs + (wx * 64 + nt * 16 + lm) * 64 + slot);
            #pragma unroll
            for (int mt = 0; mt < 4; ++mt)
                #pragma unroll
                for (int nt = 0; nt < 4; ++nt)
                    acc[mt][nt] = MFMA16(aF[mt], bF[nt], acc[mt][nt]);
        }
    }
    if (blockIdx.x < 32) {
        // full-token rows: packed atomic argmax
        #pragma unroll
        for (int mt = 0; mt < 4; ++mt)
            #pragma unroll
            for (int reg = 0; reg < 4; ++reg) {
                float bv = -FLT_MAX; int bi = 0;
                #pragma unroll
                for (int nt = 0; nt < 4; ++nt) {
                    float v = acc[mt][nt][reg];
                    int n = nB + wx * 64 + nt * 16 + lm;
                    if (v > bv) { bv = v; bi = n; }
                }
                #pragma unroll
                for (int off = 1; off < 16; off <<= 1) {
                    float ov = __shfl_xor(bv, off);
                    int oi = __shfl_xor(bi, off);
                    if (ov > bv || (ov == bv && oi < bi)) { bv = ov; bi = oi; }
                }
                if (lm == 0) {
                    unsigned ub = __float_as_uint(bv);
                    ub = (ub & 0x80000000u) ? ~ub : (ub | 0x80000000u);
                    u64 key = ((u64)ub << 32) | (u64)(0xFFFFFFFFu - (unsigned)bi);
                    int tok = mB + wy * 64 + mt * 16 + quad * 4 + reg;
                    atomicMax(&packed[tok], key);
                }
            }
    } else {
        // pooled rows: bf16 logit rows for candidate rescore
        #pragma unroll
        for (int mt = 0; mt < 4; ++mt)
            #pragma unroll
            for (int reg = 0; reg < 4; ++reg) {
                int tok = mB + wy * 64 + mt * 16 + quad * 4 + reg;
                long long base = (long long)(tok - NFULL) * 4096;
                #pragma unroll
                for (int nt = 0; nt < 4; ++nt)
                    Lp[base + nB + wx * 64 + nt * 16 + lm] =
                        __float2bfloat16(acc[mt][nt][reg]);
            }
    }
}

// ======================= tail: rescore | hist+perplexity ===================
__global__ __launch_bounds__(256) void tail_k(
    const float* __restrict__ Qpool, const float* __restrict__ Kn,
    const __hip_bfloat16* __restrict__ Lp, const unsigned int* __restrict__ Kmax2i,
    const u64* __restrict__ packed, int* __restrict__ codeP,
    float* __restrict__ outPpl) {
    __shared__ int cnt[4096];
    __shared__ float red[4];
    int tid = threadIdx.x;
    if (blockIdx.x < 256) {
        int wid = tid >> 6, lane = tid & 63;
        int tok = blockIdx.x * 4 + wid;
        const float* q = Qpool + tok * 512;
        float4 q0 = *(const float4*)(q + lane * 8);
        float4 q1 = *(const float4*)(q + lane * 8 + 4);
        float qs = q0.x * q0.x + q0.y * q0.y + q0.z * q0.z + q0.w * q0.w +
                   q1.x * q1.x + q1.y * q1.y + q1.z * q1.z + q1.w * q1.w;
        #pragma unroll
        for (int o = 32; o > 0; o >>= 1) qs += __shfl_xor(qs, o);
        float delta = 0.0078125f * sqrtf(qs) * sqrtf(__uint_as_float(*Kmax2i));
        const __hip_bfloat16* row = Lp + (long long)tok * 4096;
        float mx = -FLT_MAX;
        for (int c = 0; c < 64; ++c)
            mx = fmaxf(mx, __bfloat162float(row[c * 64 + lane]));
        #pragma unroll
        for (int o = 32; o > 0; o >>= 1) mx = fmaxf(mx, __shfl_xor(mx, o));
        float thr = mx - delta;
        float bv = -FLT_MAX; int bi = 0;
        for (int c = 0; c < 64; ++c) {
            float v = __bfloat162float(row[c * 64 + lane]);
            u64 mask = __ballot(v >= thr);
            while (mask) {
                int l = __ffsll((long long)mask) - 1;
                mask &= mask - 1;
                int n = c * 64 + l;
                const float* k = Kn + n * 512;
                float4 k0 = *(const float4*)(k + lane * 8);
                float4 k1 = *(const float4*)(k + lane * 8 + 4);
                float d = q0.x * k0.x;
                d = fmaf(q0.y, k0.y, d); d = fmaf(q0.z, k0.z, d); d = fmaf(q0.w, k0.w, d);
                d = fmaf(q1.x, k1.x, d); d = fmaf(q1.y, k1.y, d);
                d = fmaf(q1.z, k1.z, d); d = fmaf(q1.w, k1.w, d);
                #pragma unroll
                for (int o = 32; o > 0; o >>= 1) d += __shfl_xor(d, o);
                if (d > bv) { bv = d; bi = n; }   // ascending n => first-max wins
            }
        }
        if (lane == 0) codeP[tok] = bi;
    } else {
        for (int i = tid; i < 4096; i += 256) cnt[i] = 0;
        __syncthreads();
        for (int i = tid; i < 4096; i += 256) {
            int bi = (int)(0xFFFFFFFFu - (unsigned)(packed[i] & 0xFFFFFFFFu));
            atomicAdd(&cnt[bi], 1);
        }
        __syncthreads();
        float s = 0.f;
        for (int i = tid; i < 4096; i += 256) {
            float p = (float)cnt[i] * (1.0f / 4096.0f);
            s += p * logf(p + 1e-7f);
        }
        #pragma unroll
        for (int o = 32; o > 0; o >>= 1) s += __shfl_xor(s, o);
        if ((tid & 63) == 0) red[tid >> 6] = s;
        __syncthreads();
        if (tid == 0)
            outPpl[0] = expf(-(red[0] + red[1] + red[2] + red[3]));
    }
}

// ======================= z_hat: wave per (b, j) ============================
__global__ void zhat_k(const float* __restrict__ Vv, const int* __restrict__ codeP,
                       float* __restrict__ out) {
    int w = (blockIdx.x << 2) + (threadIdx.x >> 6);   // 0..1023
    int lane = threadIdx.x & 63;
    int b = w >> 8, j = w & 255;
    const int* cb = codeP + (b << 8);
    const float* rm = Vv + cb[max(j - 1, 0)] * 512;
    const float* r0 = Vv + cb[j] * 512;
    const float* rp = Vv + cb[min(j + 1, 255)] * 512;
    #pragma unroll
    for (int i = 0; i < 8; ++i) {
        int c = i * 64 + lane;
        float vm = rm[c], v0 = r0[c], vp = rp[c];
        float4 o;
        o.x = 0.375f * vm + 0.625f * v0;
        o.y = 0.125f * vm + 0.875f * v0;
        o.z = 0.875f * v0 + 0.125f * vp;
        o.w = 0.625f * v0 + 0.375f * vp;
        *(float4*)&out[(((b << 9) + c) << 10) + (j << 2)] = o;
    }
}

extern "C" void kernel_launch(void* const* d_in, const int* in_sizes, int n_in,
                              void* d_out, int out_size, void* d_ws, size_t ws_size,
                              hipStream_t stream) {
    const float* z   = (const float*)d_in[0];
    const float* cbk = (const float*)d_in[2];
    const float* Wq  = (const float*)d_in[3];
    const float* bq  = (const float*)d_in[4];
    const float* Wk  = (const float*)d_in[5];
    const float* bk  = (const float*)d_in[6];
    const float* Wv  = (const float*)d_in[7];
    const float* bv  = (const float*)d_in[8];
    const float* Wp  = (const float*)d_in[9];
    const float* bp  = (const float*)d_in[10];
    const float* gq  = (const float*)d_in[11];
    const float* gk  = (const float*)d_in[12];
    float* out = (float*)d_out;

    // ---- workspace layout ----
    float* X      = (float*)d_ws;            // 5120*512 (only pooled rows used)
    float* Qpool  = X + 5120 * 512;          // 1024*512
    float* Kn     = Qpool + 1024 * 512;      // 4096*512
    float* Vb     = Kn + 4096 * 512;         // 4096*512
    float* Cp     = Vb + 4096 * 512;         // 5120*8
    float* P0     = Cp + 5120 * 8;           // 5120*512 (aliased by Lp later)
    float* P1     = P0 + 5120 * 512;         // 5120*512
    u64*   packed = (u64*)(P1 + 5120 * 512); // 4096
    unsigned int* Kmax2i = (unsigned int*)(packed + 4096);  // 4
    int*   codeP  = (int*)(Kmax2i + 4);      // 1024
    __hip_bfloat16* Qh  = (__hip_bfloat16*)(codeP + 1024);  // 5120*512
    __hip_bfloat16* Kh  = Qh + 5120 * 512;   // 4096*512
    __hip_bfloat16* Xh  = Kh + 4096 * 512;   // 4096*512
    __hip_bfloat16* cbh = Xh + 4096 * 512;   // 4096*512
    __hip_bfloat16* WqT = cbh + 4096 * 512;  // 512*512
    __hip_bfloat16* WvT = WqT + 512 * 512;   // 512*512
    __hip_bfloat16* Lp  = (__hip_bfloat16*)P0;  // alias: 1024*4096 bf16

    prep_k<<<4624, 256, 0, stream>>>(z, cbk, Wq, Wv, X, Xh, cbh, WqT, WvT,
                                     packed, Kmax2i);
    mid1_k<<<1920, 256, 0, stream>>>(Xh, cbk, X + 4096 * 512, Wk, Wq, Wp, bp,
                                     P0, P1, Cp);
    mid2_k<<<1536, 256, 0, stream>>>(Xh, WqT, cbh, WvT, P0, P1, bk, bq, gk, gq,
                                     Cp, bv, Qh, Vb, Kn, Kh, Qpool, Kmax2i);
    logits_full_k<<<dim3(40, 16), 512, 0, stream>>>(Qh, Kh, packed, Lp);
    tail_k<<<257, 256, 0, stream>>>(Qpool, Kn, Lp, Kmax2i, packed, codeP,
                                    out + 4 * 512 * 1024);
    zhat_k<<<256, 256, 0, stream>>>(Vb, codeP, out);
}

// Round 8
// 222.995 us; speedup vs baseline: 1.1182x; 1.0030x over previous
//
#include <hip/hip_runtime.h>
#include <hip/hip_bf16.h>
#include <cfloat>
#include <math.h>

#define NFULL 4096
#define NPOOL 1024
#define NTOK  5120
#define VDIM  4096

typedef __attribute__((ext_vector_type(8))) short short8;   // 8 bf16 (4 VGPR)
typedef __attribute__((ext_vector_type(4))) float f4;       // MFMA acc
typedef unsigned long long u64;

#define MFMA16(a,b,c) __builtin_amdgcn_mfma_f32_16x16x32_bf16((a),(b),(c),0,0,0)

static __device__ __forceinline__ void gl_lds16(const void* g, void* l) {
    __builtin_amdgcn_global_load_lds(
        (const __attribute__((address_space(1))) unsigned int*)g,
        (__attribute__((address_space(3))) unsigned int*)l, 16, 0, 0);
}

// ==== bf16 MFMA 128x128 core, BK=64, XOR-swizzled LDS (r4-verified) ========
// Requires As, Bs to span 128*64 bf16 (16 KB) EACH.  Single-buffered,
// 2 barriers per K-step.  Used by mid2_k (proven; limits blast radius).
#define BGEMM3_CORE(AM, Bt)                                                    \
    int lane = tid & 63, w = tid >> 6, wy = w >> 1, wx = w & 1;                \
    int lm = lane & 15, quad = lane >> 4;                                      \
    int lr8 = lane >> 3;                                                       \
    int kcs = (lane & 7) ^ lr8;                                                \
    int rS = w * 32 + lr8;                                                     \
    const __hip_bfloat16* Ag = (AM) + (mB + rS) * 512 + kcs * 8;               \
    const __hip_bfloat16* Bg = (Bt) + (nB + rS) * 512 + kcs * 8;               \
    __hip_bfloat16* Al = As + (w * 32) * 64 + lane * 8;                        \
    __hip_bfloat16* Bl = Bs + (w * 32) * 64 + lane * 8;                        \
    f4 acc[4][4];                                                              \
    _Pragma("unroll") for (int i = 0; i < 4; ++i)                              \
        _Pragma("unroll") for (int j = 0; j < 4; ++j)                          \
            acc[i][j] = f4{0.f, 0.f, 0.f, 0.f};                                \
    int aswz = lm & 7;                                                         \
    for (int kt = 0; kt < 8; ++kt) {                                           \
        __syncthreads();                                                       \
        _Pragma("unroll") for (int i = 0; i < 4; ++i) {                        \
            gl_lds16(Ag + kt * 64 + i * 8 * 512, Al + i * 8 * 64);             \
            gl_lds16(Bg + kt * 64 + i * 8 * 512, Bl + i * 8 * 64);             \
        }                                                                      \
        __syncthreads();                                                       \
        _Pragma("unroll") for (int s = 0; s < 2; ++s) {                        \
            short8 aF[4], bF[4];                                               \
            int slot = ((s * 4 + quad) ^ aswz) << 3;                           \
            _Pragma("unroll") for (int mt = 0; mt < 4; ++mt)                   \
                aF[mt] = *(const short8*)(As + (wy * 64 + mt * 16 + lm) * 64 + slot); \
            _Pragma("unroll") for (int nt = 0; nt < 4; ++nt)                   \
                bF[nt] = *(const short8*)(Bs + (wx * 64 + nt * 16 + lm) * 64 + slot); \
            _Pragma("unroll") for (int mt = 0; mt < 4; ++mt)                   \
                _Pragma("unroll") for (int nt = 0; nt < 4; ++nt)               \
                    acc[mt][nt] = MFMA16(aF[mt], bF[nt], acc[mt][nt]);         \
        }                                                                      \
    }

// ======================= prep: transposes + casts + zero-init ==============
__global__ void prep_k(const float* __restrict__ z, const float* __restrict__ cbk,
                       const float* __restrict__ Wq, const float* __restrict__ Wv,
                       float* __restrict__ X, __hip_bfloat16* __restrict__ Xh,
                       __hip_bfloat16* __restrict__ cbh,
                       __hip_bfloat16* __restrict__ WqT, __hip_bfloat16* __restrict__ WvT,
                       u64* __restrict__ packed, unsigned int* __restrict__ Kmax2i) {
    __shared__ float smem[33 * 32];
    int bx = blockIdx.x;
    if (bx < 2048) {
        float (*tile)[33] = (float(*)[33])smem;
        int t0 = (bx & 31) * 32, c0 = ((bx >> 5) & 15) * 32, b = bx >> 9;
        int tx = threadIdx.x & 31, ty = threadIdx.x >> 5;
        #pragma unroll
        for (int i = 0; i < 4; ++i) {
            int c = ty + i * 8;
            tile[c][tx] = z[((b << 9) + c0 + c) * 1024 + t0 + tx];
        }
        __syncthreads();
        #pragma unroll
        for (int i = 0; i < 4; ++i) {
            int tl = ty + i * 8;
            int tok = (b << 10) + t0 + tl;
            Xh[tok * 512 + c0 + tx] = __float2bfloat16(tile[tx][tl]);
        }
        float m = 0.25f * (tile[tx][ty * 4] + tile[tx][ty * 4 + 1] +
                           tile[tx][ty * 4 + 2] + tile[tx][ty * 4 + 3]);
        int tq = (t0 >> 2) + ty;
        X[(NFULL + (b << 8) + tq) * 512 + c0 + tx] = m;
    } else if (bx < 4096) {
        int i0 = (bx - 2048) * 1024 + threadIdx.x * 4;
        float4 v = *(const float4*)(cbk + i0);
        __hip_bfloat16* d = cbh + i0;
        d[0] = __float2bfloat16(v.x); d[1] = __float2bfloat16(v.y);
        d[2] = __float2bfloat16(v.z); d[3] = __float2bfloat16(v.w);
    } else if (bx < 4608) {
        int lin = bx - 4096;
        const float* W = (lin >> 8) ? Wv : Wq;
        __hip_bfloat16* WT = (lin >> 8) ? WvT : WqT;
        float (*t)[33] = (float(*)[33])smem;
        int bk = ((lin >> 4) & 15) * 32, bn = (lin & 15) * 32;
        int lx = threadIdx.x & 31, ly = threadIdx.x >> 5;
        #pragma unroll
        for (int i = 0; i < 4; ++i) {
            int r = ly * 4 + i;
            t[r][lx] = W[(bk + r) * 512 + bn + lx];
        }
        __syncthreads();
        #pragma unroll
        for (int i = 0; i < 4; ++i) {
            int r = ly * 4 + i;
            WT[(bn + r) * 512 + bk + lx] = __float2bfloat16(t[lx][r]);
        }
    } else {
        int i = (bx - 4608) * 256 + threadIdx.x;     // 0..4095
        packed[i] = 0ull;
        if (bx == 4608 && threadIdx.x == 0) Kmax2i[0] = 0u;
    }
}

// ======================= mid1: fp32 proj | pool-c (both depend on prep) ====
// r17: (a) loop-rotated prefetch (kt+1 regs loaded right after store-barrier,
// hidden under the 16-kk compute -- the old layout exposed full L2/L3
// latency every kt); (b) split-K=4 for the codebook rows (80% of FLOPs):
// 1024 K-blocks + 128 Q-blocks (split-2) = 1152 gemm blocks -> 4.5/CU
// residency (was 640 -> 2.5).  Partial buffers P2/P3 ALIAS dead memory:
// P2 == Kn (norm-finish reads P2[row] then writes Kn[row] -- row-exclusive,
// read-before-write in-thread), P3 == X rows 0..4095 (prep/mid1 only touch
// X rows 4096+).  Zero new workspace.  fp32 kept: the tail rescore's
// tie-breaking needs fp32-exact K/Qpool.
__global__ __launch_bounds__(256) void mid1_k(
    const __hip_bfloat16* __restrict__ Xh,
    const float* __restrict__ cbk, const float* __restrict__ Xp,
    const float* __restrict__ Wk, const float* __restrict__ Wq,
    const float* __restrict__ Wp, const float* __restrict__ bp,
    float* __restrict__ P0, float* __restrict__ P1,
    float* __restrict__ P2, float* __restrict__ P3,
    float* __restrict__ Cp) {
    __shared__ __align__(16) char smraw[16640];
    int bx = blockIdx.x, tid = threadIdx.x;
    if (bx < 1152) {
        // ---------------- fp32 split-K projection ---------------------------
        float (*As2)[68]  = (float(*)[68])smraw;
        float (*Bs2)[132] = (float(*)[132])(smraw + 16 * 68 * 4);
        const float *A, *B; float* P;
        int mB, nB, kOff, nkt;
        if (bx < 1024) {
            // codebook rows: split-K=4, K-slice 128, 8 kt
            int part = bx >> 8, rem = bx & 255;
            mB = (rem & 63) * 64; nB = (rem >> 6) * 128;
            kOff = part * 128; nkt = 8;
            A = cbk + mB * 512; B = Wk;
            P = (part == 0) ? P0 : (part == 1) ? P1 : (part == 2) ? P2 : P3;
        } else {
            // pooled-Q rows: split-K=2, K-slice 256, 16 kt
            int lin = bx - 1024;
            int part = lin >> 6, rem = lin & 63;
            mB = NFULL + (rem & 15) * 64; nB = (rem >> 4) * 128;
            kOff = part * 256; nkt = 16;
            A = Xp + (rem & 15) * 64 * 512; B = Wq;
            P = part ? P1 : P0;
        }
        int ty = tid >> 4, tx = tid & 15;
        int arow = tid >> 2, achk = tid & 3;
        int brow = tid >> 4, bcol = (tid & 15) * 4;
        const float* Ap = A + arow * 512 + kOff + achk * 4;
        const float* Bp = B + (kOff + brow) * 512 + nB + bcol;
        float acc[4][8] = {};
        float4 a  = *(const float4*)(Ap);
        float4 b0 = *(const float4*)(Bp);
        float4 b1 = *(const float4*)(Bp + 64);
        for (int kt = 0; kt < nkt; ++kt) {
            __syncthreads();
            As2[achk * 4 + 0][arow] = a.x; As2[achk * 4 + 1][arow] = a.y;
            As2[achk * 4 + 2][arow] = a.z; As2[achk * 4 + 3][arow] = a.w;
            *(float4*)&Bs2[brow][bcol]      = b0;
            *(float4*)&Bs2[brow][bcol + 64] = b1;
            __syncthreads();
            if (kt + 1 < nkt) {   // prefetch kt+1 -- hidden under 16-kk compute
                a  = *(const float4*)(Ap + (kt + 1) * 16);
                b0 = *(const float4*)(Bp + (kt + 1) * 16 * 512);
                b1 = *(const float4*)(Bp + (kt + 1) * 16 * 512 + 64);
            }
            #pragma unroll
            for (int kk = 0; kk < 16; ++kk) {
                float4 av  = *(const float4*)&As2[kk][ty * 4];
                float4 bv0 = *(const float4*)&Bs2[kk][tx * 4];
                float4 bv1 = *(const float4*)&Bs2[kk][64 + tx * 4];
                float a4[4] = {av.x, av.y, av.z, av.w};
                float b8[8] = {bv0.x, bv0.y, bv0.z, bv0.w, bv1.x, bv1.y, bv1.z, bv1.w};
                #pragma unroll
                for (int i = 0; i < 4; ++i)
                    #pragma unroll
                    for (int j = 0; j < 8; ++j)
                        acc[i][j] = fmaf(a4[i], b8[j], acc[i][j]);
            }
        }
        #pragma unroll
        for (int i = 0; i < 4; ++i) {
            int row = mB + ty * 4 + i;
            float4 r0, r1;
            r0.x = acc[i][0]; r0.y = acc[i][1]; r0.z = acc[i][2]; r0.w = acc[i][3];
            r1.x = acc[i][4]; r1.y = acc[i][5]; r1.z = acc[i][6]; r1.w = acc[i][7];
            *(float4*)&P[row * 512 + nB + tx * 4]      = r0;
            *(float4*)&P[row * 512 + nB + 64 + tx * 4] = r1;
        }
    } else {
        // ---------------- head-pool weights Cp ------------------------------
        float* Wl = (float*)smraw;             // 4160 floats: lane stride 65
        for (int i = tid; i < 4096; i += 256) Wl[i + (i >> 6)] = Wp[i];
        __syncthreads();
        int w = tid >> 6, lane = tid & 63;
        int tok = (bx - 1152) * 4 + w;         // 0..5119
        float x[8];
        if (tok < NFULL) {
            short8 xv = *(const short8*)(Xh + tok * 512 + lane * 8);
            #pragma unroll
            for (int j = 0; j < 8; ++j)
                x[j] = __uint_as_float(((unsigned)(unsigned short)xv[j]) << 16);
        } else {
            const float* xp = Xp + (tok - NFULL) * 512 + lane * 8;
            float4 a = *(const float4*)xp, b = *(const float4*)(xp + 4);
            x[0] = a.x; x[1] = a.y; x[2] = a.z; x[3] = a.w;
            x[4] = b.x; x[5] = b.y; x[6] = b.z; x[7] = b.w;
        }
        float s[8] = {};
        int base = lane * 65;
        #pragma unroll
        for (int j = 0; j < 8; ++j)
            #pragma unroll
            for (int h = 0; h < 8; ++h)
                s[h] = fmaf(x[j], Wl[base + j * 8 + h], s[h]);
        #pragma unroll
        for (int h = 0; h < 8; ++h)
            #pragma unroll
            for (int o = 32; o > 0; o >>= 1) s[h] += __shfl_xor(s[h], o);
        if (lane == 0) {
            #pragma unroll
            for (int h = 0; h < 8; ++h) Cp[tok * 8 + h] = s[h] + bp[h];
        }
    }
}

// ======================= mid2: bf16 bgemms | split-K norm-finish ===========
// [0,256): MFMA GEMMs (Qproj+norm reads Cp - ordered after mid1; Vproj).
// [256,1536): norm-finish, WAVE-PER-ROW, 4 rows/block.  K rows reduce
// P0+P1+P2+P3 (r17 4-way split-K); Q rows reduce P0+P1.
// NOTE: P2 aliases Kn (read-before-write per row) -- NO __restrict__ on
// P2/Kn, or the compiler may reorder the store above the load.
// NOTE: smraw MUST be 32768 B — BGEMM3_CORE uses As (16 KB) + Bs (16 KB).
__global__ __launch_bounds__(256) void mid2_k(
    const __hip_bfloat16* __restrict__ Xh, const __hip_bfloat16* __restrict__ WqT,
    const __hip_bfloat16* __restrict__ cbh, const __hip_bfloat16* __restrict__ WvT,
    const float* __restrict__ P0, const float* __restrict__ P1,
    const float* P2, const float* __restrict__ P3,
    const float* __restrict__ bk, const float* __restrict__ bq,
    const float* __restrict__ gk, const float* __restrict__ gq,
    const float* __restrict__ Cp, const float* __restrict__ bvv,
    __hip_bfloat16* __restrict__ Qh, float* __restrict__ Vb,
    float* Kn, __hip_bfloat16* __restrict__ Kh,
    float* __restrict__ Qpool, unsigned int* __restrict__ Kmax2i) {
    __shared__ __align__(16) char smraw[32768];
    int bx = blockIdx.x, tid = threadIdx.x;
    if (bx < 256) {
        int part = bx >> 7, rem = bx & 127;
        int mB = (rem & 31) * 128, nB = (rem >> 5) * 128;
        const __hip_bfloat16* AM = part ? cbh : Xh;
        const __hip_bfloat16* Bt = part ? WvT : WqT;
        __hip_bfloat16* As = (__hip_bfloat16*)smraw;
        __hip_bfloat16* Bs = As + 128 * 64;
        BGEMM3_CORE(AM, Bt)
        if (part == 0) {
            int h = (rem >> 5) * 2 + wx;
            float bb[4], gg[4];
            #pragma unroll
            for (int nt = 0; nt < 4; ++nt) {
                bb[nt] = bq[h * 64 + nt * 16 + lm];
                gg[nt] = gq[nt * 16 + lm];
            }
            #pragma unroll
            for (int mt = 0; mt < 4; ++mt)
                #pragma unroll
                for (int reg = 0; reg < 4; ++reg) {
                    int tok = mB + wy * 64 + mt * 16 + quad * 4 + reg;
                    float vv[4], ss = 0.f;
                    #pragma unroll
                    for (int nt = 0; nt < 4; ++nt) {
                        vv[nt] = acc[mt][nt][reg] + bb[nt];
                        ss = fmaf(vv[nt], vv[nt], ss);
                    }
                    #pragma unroll
                    for (int off = 1; off < 16; off <<= 1) ss += __shfl_xor(ss, off);
                    float sc = rsqrtf(ss * (1.0f / 64.0f) + 1e-5f) *
                               Cp[tok * 8 + h] * 0.04419417382415922f;  // 1/(8*sqrt8)
                    #pragma unroll
                    for (int nt = 0; nt < 4; ++nt)
                        Qh[tok * 512 + h * 64 + nt * 16 + lm] =
                            __float2bfloat16(vv[nt] * sc * gg[nt]);
                }
        } else {
            float bb[4];
            #pragma unroll
            for (int nt = 0; nt < 4; ++nt) bb[nt] = bvv[nB + wx * 64 + nt * 16 + lm];
            #pragma unroll
            for (int mt = 0; mt < 4; ++mt)
                #pragma unroll
                for (int reg = 0; reg < 4; ++reg) {
                    int m = mB + wy * 64 + mt * 16 + quad * 4 + reg;
                    #pragma unroll
                    for (int nt = 0; nt < 4; ++nt)
                        Vb[m * 512 + nB + wx * 64 + nt * 16 + lm] =
                            acc[mt][nt][reg] + bb[nt];
                }
        }
    } else {
        // ---------------- split-K reduce + rmsnorm (wave-per-row) -----------
        int w = tid >> 6, lane = tid & 63;
        int row = (bx - 256) * 4 + w;      // 0..5119
        bool isQ = row >= NFULL;
        const float* bias = isQ ? bq : bk;
        const float* g = isQ ? gq : gk;
        int c0 = lane * 8;                 // 8 contiguous cols per lane
        const float* p0 = P0 + row * 512 + c0;
        const float* p1 = P1 + row * 512 + c0;
        float4 a0 = *(const float4*)p0,  a1 = *(const float4*)(p0 + 4);
        float4 d0 = *(const float4*)p1,  d1 = *(const float4*)(p1 + 4);
        float4 e0 = *(const float4*)(bias + c0), e1 = *(const float4*)(bias + c0 + 4);
        int gi = (lane & 7) * 8;
        float4 g0 = *(const float4*)(g + gi), g1 = *(const float4*)(g + gi + 4);
        float v[8];
        v[0] = a0.x + d0.x + e0.x; v[1] = a0.y + d0.y + e0.y;
        v[2] = a0.z + d0.z + e0.z; v[3] = a0.w + d0.w + e0.w;
        v[4] = a1.x + d1.x + e1.x; v[5] = a1.y + d1.y + e1.y;
        v[6] = a1.z + d1.z + e1.z; v[7] = a1.w + d1.w + e1.w;
        if (!isQ) {                        // K rows: 4-way split-K
            const float* p2 = P2 + row * 512 + c0;
            const float* p3 = P3 + row * 512 + c0;
            float4 x0 = *(const float4*)p2, x1 = *(const float4*)(p2 + 4);
            float4 y0 = *(const float4*)p3, y1 = *(const float4*)(p3 + 4);
            v[0] += x0.x + y0.x; v[1] += x0.y + y0.y;
            v[2] += x0.z + y0.z; v[3] += x0.w + y0.w;
            v[4] += x1.x + y1.x; v[5] += x1.y + y1.y;
            v[6] += x1.z + y1.z; v[7] += x1.w + y1.w;
        }
        // per-head (64-col) sum-of-squares: 8 lanes per head
        float ss = 0.f;
        #pragma unroll
        for (int j = 0; j < 8; ++j) ss = fmaf(v[j], v[j], ss);
        ss += __shfl_xor(ss, 1); ss += __shfl_xor(ss, 2); ss += __shfl_xor(ss, 4);
        float sc = rsqrtf(ss * (1.0f / 64.0f) + 1e-5f);
        float gg[8] = {g0.x, g0.y, g0.z, g0.w, g1.x, g1.y, g1.z, g1.w};
        float o_[8];
        #pragma unroll
        for (int j = 0; j < 8; ++j) o_[j] = v[j] * sc * gg[j];
        if (isQ) {
            float cf = Cp[row * 8 + (lane >> 3)] * 0.04419417382415922f;
            #pragma unroll
            for (int j = 0; j < 8; ++j) o_[j] *= cf;
            float* qp = Qpool + (row - NFULL) * 512 + c0;
            *(float4*)qp       = make_float4(o_[0], o_[1], o_[2], o_[3]);
            *(float4*)(qp + 4) = make_float4(o_[4], o_[5], o_[6], o_[7]);
            __hip_bfloat16 hb[8];
            #pragma unroll
            for (int j = 0; j < 8; ++j) hb[j] = __float2bfloat16(o_[j]);
            *(short8*)(Qh + row * 512 + c0) = *(const short8*)hb;
        } else {
            float* kp = Kn + row * 512 + c0;
            *(float4*)kp       = make_float4(o_[0], o_[1], o_[2], o_[3]);
            *(float4*)(kp + 4) = make_float4(o_[4], o_[5], o_[6], o_[7]);
            __hip_bfloat16 hb[8];
            #pragma unroll
            for (int j = 0; j < 8; ++j) hb[j] = __float2bfloat16(o_[j]);
            *(short8*)(Kh + row * 512 + c0) = *(const short8*)hb;
            float rs = 0.f;
            #pragma unroll
            for (int j = 0; j < 8; ++j) rs = fmaf(o_[j], o_[j], rs);
            #pragma unroll
            for (int o = 32; o > 0; o >>= 1) rs += __shfl_xor(rs, o);
            float* wsum = (float*)smraw;
            if (lane == 0) wsum[w] = rs;
            __syncthreads();
            if (tid == 0) {
                float m01 = fmaxf(wsum[0], wsum[1]);
                float m23 = fmaxf(wsum[2], wsum[3]);
                atomicMax(Kmax2i, __float_as_uint(fmaxf(m01, m23)));
            }
        }
    }
}

// ==== logits over all 5120 tokens ==========================================
// r16: ASYMMETRIC 128x256 tile, BK=64, 512 threads (8 waves, 2m x 4n,
// per-wave 64x64 -> acc[4][4]).  0.75x staged bytes of 128^2 at the SAME
// 2-blocks/CU residency (48 KB LDS).  Verified winner (logits left top-5).
__global__ __launch_bounds__(512, 4) void logits_full_k(
    const __hip_bfloat16* __restrict__ Qh, const __hip_bfloat16* __restrict__ Kh,
    u64* __restrict__ packed, __hip_bfloat16* __restrict__ Lp) {
    __shared__ __hip_bfloat16 As[128 * 64];   // 16 KB
    __shared__ __hip_bfloat16 Bs[256 * 64];   // 32 KB
    int tid = threadIdx.x;
    int mB = blockIdx.x * 128, nB = blockIdx.y * 256;   // grid (40, 16)
    int lane = tid & 63, w = tid >> 6;        // 8 waves
    int wy = w >> 2, wx = w & 3;              // wy: m-half (64), wx: n-quarter (64)
    int lm = lane & 15, quad = lane >> 4;
    int lr8 = lane >> 3;
    int kcs = (lane & 7) ^ lr8;               // XOR-swizzled source col-chunk
    const __hip_bfloat16* Ag = Qh + (mB + w * 16 + lr8) * 512 + kcs * 8;
    const __hip_bfloat16* Bg = Kh + (nB + w * 32 + lr8) * 512 + kcs * 8;
    __hip_bfloat16* Al = As + (w * 16) * 64 + lane * 8;
    __hip_bfloat16* Bl = Bs + (w * 32) * 64 + lane * 8;
    f4 acc[4][4];
    #pragma unroll
    for (int i = 0; i < 4; ++i)
        #pragma unroll
        for (int j = 0; j < 4; ++j) acc[i][j] = f4{0.f, 0.f, 0.f, 0.f};
    int aswz = lm & 7;
    for (int kt = 0; kt < 8; ++kt) {
        __syncthreads();
        #pragma unroll
        for (int i = 0; i < 2; ++i)           // A: 8 waves x 16 rows = 128
            gl_lds16(Ag + kt * 64 + i * 8 * 512, Al + i * 8 * 64);
        #pragma unroll
        for (int i = 0; i < 4; ++i)           // B: 8 waves x 32 rows = 256
            gl_lds16(Bg + kt * 64 + i * 8 * 512, Bl + i * 8 * 64);
        __syncthreads();
        #pragma unroll
        for (int s = 0; s < 2; ++s) {
            short8 aF[4], bF[4];
            int slot = ((s * 4 + quad) ^ aswz) << 3;
            #pragma unroll
            for (int mt = 0; mt < 4; ++mt)
                aF[mt] = *(const short8*)(As + (wy * 64 + mt * 16 + lm) * 64 + slot);
            #pragma unroll
            for (int nt = 0; nt < 4; ++nt)
                bF[nt] = *(const short8*)(Bs + (wx * 64 + nt * 16 + lm) * 64 + slot);
            #pragma unroll
            for (int mt = 0; mt < 4; ++mt)
                #pragma unroll
                for (int nt = 0; nt < 4; ++nt)
                    acc[mt][nt] = MFMA16(aF[mt], bF[nt], acc[mt][nt]);
        }
    }
    if (blockIdx.x < 32) {
        // full-token rows: packed atomic argmax
        #pragma unroll
        for (int mt = 0; mt < 4; ++mt)
            #pragma unroll
            for (int reg = 0; reg < 4; ++reg) {
                float bv = -FLT_MAX; int bi = 0;
                #pragma unroll
                for (int nt = 0; nt < 4; ++nt) {
                    float v = acc[mt][nt][reg];
                    int n = nB + wx * 64 + nt * 16 + lm;
                    if (v > bv) { bv = v; bi = n; }
                }
                #pragma unroll
                for (int off = 1; off < 16; off <<= 1) {
                    float ov = __shfl_xor(bv, off);
                    int oi = __shfl_xor(bi, off);
                    if (ov > bv || (ov == bv && oi < bi)) { bv = ov; bi = oi; }
                }
                if (lm == 0) {
                    unsigned ub = __float_as_uint(bv);
                    ub = (ub & 0x80000000u) ? ~ub : (ub | 0x80000000u);
                    u64 key = ((u64)ub << 32) | (u64)(0xFFFFFFFFu - (unsigned)bi);
                    int tok = mB + wy * 64 + mt * 16 + quad * 4 + reg;
                    atomicMax(&packed[tok], key);
                }
            }
    } else {
        // pooled rows: bf16 logit rows for candidate rescore
        #pragma unroll
        for (int mt = 0; mt < 4; ++mt)
            #pragma unroll
            for (int reg = 0; reg < 4; ++reg) {
                int tok = mB + wy * 64 + mt * 16 + quad * 4 + reg;
                long long base = (long long)(tok - NFULL) * 4096;
                #pragma unroll
                for (int nt = 0; nt < 4; ++nt)
                    Lp[base + nB + wx * 64 + nt * 16 + lm] =
                        __float2bfloat16(acc[mt][nt][reg]);
            }
    }
}

// ======================= tail: rescore | hist+perplexity ===================
__global__ __launch_bounds__(256) void tail_k(
    const float* __restrict__ Qpool, const float* __restrict__ Kn,
    const __hip_bfloat16* __restrict__ Lp, const unsigned int* __restrict__ Kmax2i,
    const u64* __restrict__ packed, int* __restrict__ codeP,
    float* __restrict__ outPpl) {
    __shared__ int cnt[4096];
    __shared__ float red[4];
    int tid = threadIdx.x;
    if (blockIdx.x < 256) {
        int wid = tid >> 6, lane = tid & 63;
        int tok = blockIdx.x * 4 + wid;
        const float* q = Qpool + tok * 512;
        float4 q0 = *(const float4*)(q + lane * 8);
        float4 q1 = *(const float4*)(q + lane * 8 + 4);
        float qs = q0.x * q0.x + q0.y * q0.y + q0.z * q0.z + q0.w * q0.w +
                   q1.x * q1.x + q1.y * q1.y + q1.z * q1.z + q1.w * q1.w;
        #pragma unroll
        for (int o = 32; o > 0; o >>= 1) qs += __shfl_xor(qs, o);
        float delta = 0.0078125f * sqrtf(qs) * sqrtf(__uint_as_float(*Kmax2i));
        const __hip_bfloat16* row = Lp + (long long)tok * 4096;
        float mx = -FLT_MAX;
        for (int c = 0; c < 64; ++c)
            mx = fmaxf(mx, __bfloat162float(row[c * 64 + lane]));
        #pragma unroll
        for (int o = 32; o > 0; o >>= 1) mx = fmaxf(mx, __shfl_xor(mx, o));
        float thr = mx - delta;
        float bv = -FLT_MAX; int bi = 0;
        for (int c = 0; c < 64; ++c) {
            float v = __bfloat162float(row[c * 64 + lane]);
            u64 mask = __ballot(v >= thr);
            while (mask) {
                int l = __ffsll((long long)mask) - 1;
                mask &= mask - 1;
                int n = c * 64 + l;
                const float* k = Kn + n * 512;
                float4 k0 = *(const float4*)(k + lane * 8);
                float4 k1 = *(const float4*)(k + lane * 8 + 4);
                float d = q0.x * k0.x;
                d = fmaf(q0.y, k0.y, d); d = fmaf(q0.z, k0.z, d); d = fmaf(q0.w, k0.w, d);
                d = fmaf(q1.x, k1.x, d); d = fmaf(q1.y, k1.y, d);
                d = fmaf(q1.z, k1.z, d); d = fmaf(q1.w, k1.w, d);
                #pragma unroll
                for (int o = 32; o > 0; o >>= 1) d += __shfl_xor(d, o);
                if (d > bv) { bv = d; bi = n; }   // ascending n => first-max wins
            }
        }
        if (lane == 0) codeP[tok] = bi;
    } else {
        for (int i = tid; i < 4096; i += 256) cnt[i] = 0;
        __syncthreads();
        for (int i = tid; i < 4096; i += 256) {
            int bi = (int)(0xFFFFFFFFu - (unsigned)(packed[i] & 0xFFFFFFFFu));
            atomicAdd(&cnt[bi], 1);
        }
        __syncthreads();
        float s = 0.f;
        for (int i = tid; i < 4096; i += 256) {
            float p = (float)cnt[i] * (1.0f / 4096.0f);
            s += p * logf(p + 1e-7f);
        }
        #pragma unroll
        for (int o = 32; o > 0; o >>= 1) s += __shfl_xor(s, o);
        if ((tid & 63) == 0) red[tid >> 6] = s;
        __syncthreads();
        if (tid == 0)
            outPpl[0] = expf(-(red[0] + red[1] + red[2] + red[3]));
    }
}

// ======================= z_hat: wave per (b, j) ============================
__global__ void zhat_k(const float* __restrict__ Vv, const int* __restrict__ codeP,
                       float* __restrict__ out) {
    int w = (blockIdx.x << 2) + (threadIdx.x >> 6);   // 0..1023
    int lane = threadIdx.x & 63;
    int b = w >> 8, j = w & 255;
    const int* cb = codeP + (b << 8);
    const float* rm = Vv + cb[max(j - 1, 0)] * 512;
    const float* r0 = Vv + cb[j] * 512;
    const float* rp = Vv + cb[min(j + 1, 255)] * 512;
    #pragma unroll
    for (int i = 0; i < 8; ++i) {
        int c = i * 64 + lane;
        float vm = rm[c], v0 = r0[c], vp = rp[c];
        float4 o;
        o.x = 0.375f * vm + 0.625f * v0;
        o.y = 0.125f * vm + 0.875f * v0;
        o.z = 0.875f * v0 + 0.125f * vp;
        o.w = 0.625f * v0 + 0.375f * vp;
        *(float4*)&out[(((b << 9) + c) << 10) + (j << 2)] = o;
    }
}

extern "C" void kernel_launch(void* const* d_in, const int* in_sizes, int n_in,
                              void* d_out, int out_size, void* d_ws, size_t ws_size,
                              hipStream_t stream) {
    const float* z   = (const float*)d_in[0];
    const float* cbk = (const float*)d_in[2];
    const float* Wq  = (const float*)d_in[3];
    const float* bq  = (const float*)d_in[4];
    const float* Wk  = (const float*)d_in[5];
    const float* bk  = (const float*)d_in[6];
    const float* Wv  = (const float*)d_in[7];
    const float* bv  = (const float*)d_in[8];
    const float* Wp  = (const float*)d_in[9];
    const float* bp  = (const float*)d_in[10];
    const float* gq  = (const float*)d_in[11];
    const float* gk  = (const float*)d_in[12];
    float* out = (float*)d_out;

    // ---- workspace layout ----
    float* X      = (float*)d_ws;            // 5120*512 (rows 0..4095 = P3 alias)
    float* Qpool  = X + 5120 * 512;          // 1024*512
    float* Kn     = Qpool + 1024 * 512;      // 4096*512 (doubles as P2)
    float* Vb     = Kn + 4096 * 512;         // 4096*512
    float* Cp     = Vb + 4096 * 512;         // 5120*8
    float* P0     = Cp + 5120 * 8;           // 5120*512 (aliased by Lp later)
    float* P1     = P0 + 5120 * 512;         // 5120*512
    u64*   packed = (u64*)(P1 + 5120 * 512); // 4096
    unsigned int* Kmax2i = (unsigned int*)(packed + 4096);  // 4
    int*   codeP  = (int*)(Kmax2i + 4);      // 1024
    __hip_bfloat16* Qh  = (__hip_bfloat16*)(codeP + 1024);  // 5120*512
    __hip_bfloat16* Kh  = Qh + 5120 * 512;   // 4096*512
    __hip_bfloat16* Xh  = Kh + 4096 * 512;   // 4096*512
    __hip_bfloat16* cbh = Xh + 4096 * 512;   // 4096*512
    __hip_bfloat16* WqT = cbh + 4096 * 512;  // 512*512
    __hip_bfloat16* WvT = WqT + 512 * 512;   // 512*512
    __hip_bfloat16* Lp  = (__hip_bfloat16*)P0;  // alias: 1024*4096 bf16
    float* P2 = Kn;                          // alias: K-rows only (0..4095)
    float* P3 = X;                           // alias: X rows 0..4095 are dead

    prep_k<<<4624, 256, 0, stream>>>(z, cbk, Wq, Wv, X, Xh, cbh, WqT, WvT,
                                     packed, Kmax2i);
    mid1_k<<<2432, 256, 0, stream>>>(Xh, cbk, X + 4096 * 512, Wk, Wq, Wp, bp,
                                     P0, P1, P2, P3, Cp);
    mid2_k<<<1536, 256, 0, stream>>>(Xh, WqT, cbh, WvT, P0, P1, P2, P3,
                                     bk, bq, gk, gq, Cp, bv,
                                     Qh, Vb, Kn, Kh, Qpool, Kmax2i);
    logits_full_k<<<dim3(40, 16), 512, 0, stream>>>(Qh, Kh, packed, Lp);
    tail_k<<<257, 256, 0, stream>>>(Qpool, Kn, Lp, Kmax2i, packed, codeP,
                                    out + 4 * 512 * 1024);
    zhat_k<<<256, 256, 0, stream>>>(Vb, codeP, out);
}